// Round 10
// baseline (381.257 us; speedup 1.0000x reference)
//
#include <hip/hip_runtime.h>
#include <hip/hip_bf16.h>

#define N_NODES_C 100000
#define FEATS 128
#define SH 10             // bucket shift: 1024 nodes per bucket (R8: SH=9 was -12us worse)
#define NBK 128           // padded bucket count (active: 98)
#define PB  256           // partition blocks
#define CAST_BLOCKS 12500 // (100000*128/4)/256

typedef unsigned int uint32;
typedef __bf16 bf16_t;
typedef bf16_t bf16x8 __attribute__((ext_vector_type(8)));
typedef float f32x4 __attribute__((ext_vector_type(4)));

union Frag { uint4 u; bf16x8 v; };

__device__ __forceinline__ unsigned short f32_to_bf16_bits(float f) {
    uint32 u = __float_as_uint(f);
    u += 0x7fffu + ((u >> 16) & 1u);   // round-to-nearest-even (finite values)
    return (unsigned short)(u >> 16);
}
__device__ __forceinline__ float bf16_lo(uint32 p) { return __uint_as_float(p << 16); }
__device__ __forceinline__ float bf16_hi(uint32 p) { return __uint_as_float(p & 0xffff0000u); }

// ---------------- Fused prep: part_count + wtprep x2 + cast ----------------
__global__ __launch_bounds__(256) void prep_fused(
    const int* __restrict__ dst, int* __restrict__ gHist, int nE, int chunk,
    const float4* __restrict__ emb4, unsigned short* __restrict__ hb0, int n4,
    const float* __restrict__ W1s, const float* __restrict__ W1n, unsigned short* __restrict__ wt1,
    const float* __restrict__ W2s, const float* __restrict__ W2n, unsigned short* __restrict__ wt2)
{
    __shared__ int h[NBK];
    const int b = blockIdx.x;
    const int tid = threadIdx.x;

    if (b < PB) {
        // --- bucket histogram over this block's edge chunk ---
        if (tid < NBK) h[tid] = 0;
        __syncthreads();
        const int b0 = b * chunk;
        const int e1 = min(b0 + chunk, nE);
        for (int e = b0 + tid; e < e1; e += 256)
            atomicAdd(&h[dst[e] >> SH], 1);
        __syncthreads();
        if (tid < NBK) gHist[tid * PB + b] = h[tid];
    } else if (b < PB + 32) {
        // --- weight pre-swizzle into B-fragment order ---
        // wt[(f*64+l)*8+j] = W[k][n], f=nt*8+ks, n=nt*16+(l&15), k=ks*32+(l>>4)*8+j
        const int which = (b - PB) >> 4;                 // 0 -> layer1, 1 -> layer2
        const float* Ws = which ? W2s : W1s;
        const float* Wn = which ? W2n : W1n;
        unsigned short* wt = which ? wt2 : wt1;
        int gid = ((b - PB) & 15) * 256 + tid;           // 0..4095
        int frag = gid >> 6, lane = gid & 63;
        int nt = frag >> 3, ks = frag & 7;
        int n = nt * 16 + (lane & 15);
        int kbase = ks * 32 + (lane >> 4) * 8;
        union { unsigned short s[8]; uint4 u; } o;
#pragma unroll
        for (int j = 0; j < 8; ++j) {
            int k = kbase + j;
            float v = (k < 128) ? Ws[(size_t)k * FEATS + n] : Wn[(size_t)(k - 128) * FEATS + n];
            o.s[j] = f32_to_bf16_bits(v);
        }
        *(uint4*)(wt + (size_t)gid * 8) = o.u;
    } else {
        // --- fp32 -> bf16 node-table cast (row-major [N][128]) ---
        int i = (b - PB - 32) * 256 + tid;
        if (i >= n4) return;
        float4 v = emb4[i];
        union { unsigned short s[4]; uint2 u; } o;
        o.s[0] = f32_to_bf16_bits(v.x);
        o.s[1] = f32_to_bf16_bits(v.y);
        o.s[2] = f32_to_bf16_bits(v.z);
        o.s[3] = f32_to_bf16_bits(v.w);
        *(uint2*)(hb0 + (size_t)i * 4) = o.u;
    }
}

// ---------------- P2: fused scan + scatter ----------------
// Every block redundantly computes the exclusive scan of gHist[32768] with the
// proven register-resident 32/thread shape (R7: runtime-loop scans are the trap,
// unrolled register scans are fine), extracts its own 128 bucket cursors via a
// statically-unrolled conditional (no dynamic reg indexing), then scatters.
// Block 0 additionally publishes bucket-boundary offsets bstart[k] (= scan value
// at flat index k*PB) for bucket_csr. Removes the scan_one dispatch + gap.
// LDS cursors only — global per-node cursors were a 250 us disaster (R7: cross-XCD
// atomic line migration + random 4-B scatter write amplification).
__global__ __launch_bounds__(1024) void part_scatter(const int* __restrict__ src,
                                                     const int* __restrict__ dst,
                                                     const int* __restrict__ gHist,
                                                     int* __restrict__ bstart,
                                                     uint32* __restrict__ ebuf,
                                                     int nE, int chunk) {
    __shared__ int ss[1024];
    __shared__ int cur[NBK];
    const int tid = threadIdx.x;
    const int base = tid * 32;
    int pref[32];
    {
        int sum = 0;
#pragma unroll
        for (int j = 0; j < 32; ++j) {
            int v = gHist[base + j];
            pref[j] = sum;
            sum += v;
        }
        ss[tid] = sum;
        __syncthreads();
        for (int d = 1; d < 1024; d <<= 1) {
            int t = (tid >= d) ? ss[tid - d] : 0;
            __syncthreads();
            ss[tid] += t;
            __syncthreads();
        }
        const int ex = ss[tid] - sum;
        // flat index f = k*PB + b (bucket-major). This block needs the scanned
        // value at f with (f & (PB-1)) == blockIdx.x, giving cursor for bucket f>>8.
#pragma unroll
        for (int j = 0; j < 32; ++j) {
            const int f = base + j;
            const int v = ex + pref[j];
            if ((f & (PB - 1)) == blockIdx.x) cur[f >> 8] = v;
        }
        if (blockIdx.x == 0) {
#pragma unroll
            for (int j = 0; j < 32; ++j) {
                const int f = base + j;
                if ((f & (PB - 1)) == 0) bstart[f >> 8] = ex + pref[j];
            }
        }
    }
    __syncthreads();
    const int b0 = blockIdx.x * chunk;
    const int e1 = min(b0 + chunk, nE);
    for (int e = b0 + tid; e < e1; e += 1024) {
        int d = dst[e];
        int pos = atomicAdd(&cur[d >> SH], 1);
        ebuf[pos] = (uint32)src[e] | ((uint32)(d & ((1 << SH) - 1)) << 17);
    }
}

// ---------------- P3: per-bucket CSR finalize ----------------
// csr stores src*256 = byte offset of the node's 256-B feature row (src < 2^17, fits 25 bits).
// SH=10: 98 blocks, full-width 1024-thread LDS scans (R8: SH=9's guarded scans were slower).
__global__ __launch_bounds__(1024) void bucket_csr(const uint32* __restrict__ ebuf,
                                                   const int* __restrict__ bstart,
                                                   int* __restrict__ off,
                                                   int* __restrict__ csr,
                                                   int nE) {
    __shared__ int cnt[1 << SH];
    __shared__ int ss[1 << SH];
    const int b = blockIdx.x;
    const int tid = threadIdx.x;
    const int start = bstart[b];
    const int end = bstart[b + 1];
    const int nodeBase = b << SH;
    cnt[tid] = 0;
    __syncthreads();
    for (int e = start + tid; e < end; e += 1024)
        atomicAdd(&cnt[ebuf[e] >> 17], 1);
    __syncthreads();
    int own = cnt[tid];
    ss[tid] = own;
    __syncthreads();
    for (int d = 1; d < 1024; d <<= 1) {
        int t = (tid >= d) ? ss[tid - d] : 0;
        __syncthreads();
        ss[tid] += t;
        __syncthreads();
    }
    int ex = ss[tid] - own;
    cnt[tid] = ex;                     // becomes placement cursor
    int node = nodeBase + tid;
    if (node < N_NODES_C) off[node] = start + ex;
    if (b == gridDim.x - 1 && tid == 0) off[N_NODES_C] = nE;
    __syncthreads();
    for (int e = start + tid; e < end; e += 1024) {
        uint32 p = ebuf[e];
        int pos = atomicAdd(&cnt[p >> 17], 1);
        csr[start + pos] = (int)((p & 0x1FFFFu) << 8);   // byte offset of src row
    }
}

// ---------------- Gather (mean aggregation over bf16 table) ----------------
// 4 nodes per 256-thread block; one wave per node; uint2 (8 B) per lane so one
// load instruction covers TWO edges' 256-B rows (lanes 0-31 = even edge,
// 32-63 = odd edge). Even/odd partials combined with shfl_xor(32) at the end.
// csr holds byte offsets (src*256): per-load address = one 64-bit add.
// PLATEAU NOTE (R3/R5/R6/R8): uint2x8, uint2x16, uint4x32 variants all land at
// 55-59 us with FETCH pinned at the 181 MB compulsory floor -> this kernel is
// at the random-256B-row memory-system ceiling (~3.8 TB/s effective). uint2x16
// is the best measured (55.5). Do not re-fuse with GEMM (earlier regression).
__global__ __launch_bounds__(256) void gather_mean_w2(const unsigned short* __restrict__ hb,
                                                      const int* __restrict__ csrB,
                                                      const int* __restrict__ off,
                                                      unsigned short* __restrict__ meanb,
                                                      int nNodes) {
    const int node = blockIdx.x * 4 + (threadIdx.x >> 6);
    const int lane = threadIdx.x & 63;
    if (node >= nNodes) return;
    const int start = __builtin_amdgcn_readfirstlane(off[node]);
    const int end   = __builtin_amdgcn_readfirstlane(off[node + 1]);
    const int half = lane >> 5;                 // which edge of a pair
    const int c = lane & 31;                    // uint2 column within 256-B row
    const char* base = (const char*)hb + (size_t)(c * 8);
    float a0 = 0.f, a1 = 0.f, a2 = 0.f, a3 = 0.f;
    int e = start;
    for (; e + 16 <= end; e += 16) {
        const int o0  = csrB[e + 0],  o1  = csrB[e + 1],  o2  = csrB[e + 2],  o3  = csrB[e + 3];
        const int o4  = csrB[e + 4],  o5  = csrB[e + 5],  o6  = csrB[e + 6],  o7  = csrB[e + 7];
        const int o8  = csrB[e + 8],  o9  = csrB[e + 9],  o10 = csrB[e + 10], o11 = csrB[e + 11];
        const int o12 = csrB[e + 12], o13 = csrB[e + 13], o14 = csrB[e + 14], o15 = csrB[e + 15];
        const uint2 u0 = *(const uint2*)(base + (size_t)(half ? o1  : o0));
        const uint2 u1 = *(const uint2*)(base + (size_t)(half ? o3  : o2));
        const uint2 u2 = *(const uint2*)(base + (size_t)(half ? o5  : o4));
        const uint2 u3 = *(const uint2*)(base + (size_t)(half ? o7  : o6));
        const uint2 u4 = *(const uint2*)(base + (size_t)(half ? o9  : o8));
        const uint2 u5 = *(const uint2*)(base + (size_t)(half ? o11 : o10));
        const uint2 u6 = *(const uint2*)(base + (size_t)(half ? o13 : o12));
        const uint2 u7 = *(const uint2*)(base + (size_t)(half ? o15 : o14));
        a0 += bf16_lo(u0.x); a1 += bf16_hi(u0.x); a2 += bf16_lo(u0.y); a3 += bf16_hi(u0.y);
        a0 += bf16_lo(u1.x); a1 += bf16_hi(u1.x); a2 += bf16_lo(u1.y); a3 += bf16_hi(u1.y);
        a0 += bf16_lo(u2.x); a1 += bf16_hi(u2.x); a2 += bf16_lo(u2.y); a3 += bf16_hi(u2.y);
        a0 += bf16_lo(u3.x); a1 += bf16_hi(u3.x); a2 += bf16_lo(u3.y); a3 += bf16_hi(u3.y);
        a0 += bf16_lo(u4.x); a1 += bf16_hi(u4.x); a2 += bf16_lo(u4.y); a3 += bf16_hi(u4.y);
        a0 += bf16_lo(u5.x); a1 += bf16_hi(u5.x); a2 += bf16_lo(u5.y); a3 += bf16_hi(u5.y);
        a0 += bf16_lo(u6.x); a1 += bf16_hi(u6.x); a2 += bf16_lo(u6.y); a3 += bf16_hi(u6.y);
        a0 += bf16_lo(u7.x); a1 += bf16_hi(u7.x); a2 += bf16_lo(u7.y); a3 += bf16_hi(u7.y);
    }
    if (e + 8 <= end) {
        const int o0 = csrB[e + 0], o1 = csrB[e + 1], o2 = csrB[e + 2], o3 = csrB[e + 3];
        const int o4 = csrB[e + 4], o5 = csrB[e + 5], o6 = csrB[e + 6], o7 = csrB[e + 7];
        const uint2 u0 = *(const uint2*)(base + (size_t)(half ? o1 : o0));
        const uint2 u1 = *(const uint2*)(base + (size_t)(half ? o3 : o2));
        const uint2 u2 = *(const uint2*)(base + (size_t)(half ? o5 : o4));
        const uint2 u3 = *(const uint2*)(base + (size_t)(half ? o7 : o6));
        a0 += bf16_lo(u0.x); a1 += bf16_hi(u0.x); a2 += bf16_lo(u0.y); a3 += bf16_hi(u0.y);
        a0 += bf16_lo(u1.x); a1 += bf16_hi(u1.x); a2 += bf16_lo(u1.y); a3 += bf16_hi(u1.y);
        a0 += bf16_lo(u2.x); a1 += bf16_hi(u2.x); a2 += bf16_lo(u2.y); a3 += bf16_hi(u2.y);
        a0 += bf16_lo(u3.x); a1 += bf16_hi(u3.x); a2 += bf16_lo(u3.y); a3 += bf16_hi(u3.y);
        e += 8;
    }
    if (e + 4 <= end) {
        const int o0 = csrB[e + 0], o1 = csrB[e + 1], o2 = csrB[e + 2], o3 = csrB[e + 3];
        const uint2 u0 = *(const uint2*)(base + (size_t)(half ? o1 : o0));
        const uint2 u1 = *(const uint2*)(base + (size_t)(half ? o3 : o2));
        a0 += bf16_lo(u0.x); a1 += bf16_hi(u0.x); a2 += bf16_lo(u0.y); a3 += bf16_hi(u0.y);
        a0 += bf16_lo(u1.x); a1 += bf16_hi(u1.x); a2 += bf16_lo(u1.y); a3 += bf16_hi(u1.y);
        e += 4;
    }
    if (e + 2 <= end) {
        const int o0 = csrB[e + 0], o1 = csrB[e + 1];
        const uint2 u = *(const uint2*)(base + (size_t)(half ? o1 : o0));
        a0 += bf16_lo(u.x); a1 += bf16_hi(u.x); a2 += bf16_lo(u.y); a3 += bf16_hi(u.y);
        e += 2;
    }
    if (e < end && half == 0) {
        const uint2 u = *(const uint2*)(base + (size_t)csrB[e]);
        a0 += bf16_lo(u.x); a1 += bf16_hi(u.x); a2 += bf16_lo(u.y); a3 += bf16_hi(u.y);
    }
    // combine even-edge / odd-edge partial sums held in lane pairs (l, l^32)
    a0 += __shfl_xor(a0, 32);
    a1 += __shfl_xor(a1, 32);
    a2 += __shfl_xor(a2, 32);
    a3 += __shfl_xor(a3, 32);
    const int deg = end - start;
    const float invd = (deg > 0) ? (1.f / (float)deg) : 0.f;
    if (half == 0) {
        uint2 o;
        o.x = ((uint32)f32_to_bf16_bits(a1 * invd) << 16) | (uint32)f32_to_bf16_bits(a0 * invd);
        o.y = ((uint32)f32_to_bf16_bits(a3 * invd) << 16) | (uint32)f32_to_bf16_bits(a2 * invd);
        ((uint2*)meanb)[(size_t)node * 32 + c] = o;
    }
}

// ---------------- MFMA SAGE GEMM (LDS-staged weights, persistent) ----------------
// 512 blocks x 512 threads = 8 waves x 16-row stripes; exactly 2 blocks/CU at
// 64 KB LDS. Weights staged ONCE per block, then a barrier-free grid-stride loop
// over 128-row stripes (LDS is read-only after the stage).
// NOTE (R4 post-mortem): 32-row/wave (a[16]+acc[16] live) blew the register
// budget -> scratch -> 2x slower. Keep the 16-row register shape.
__global__ __launch_bounds__(512) void sage_gemm_mfma(const unsigned short* __restrict__ HB,
                                                      const unsigned short* __restrict__ MB,
                                                      const unsigned short* __restrict__ WT,
                                                      const float* __restrict__ bias,
                                                      void* __restrict__ OUTP,
                                                      int nNodes, int nStripes, int mode) {
    __shared__ uint4 wtl[4096];                       // 64 KB
    const int tid = threadIdx.x;
    const uint4* wt4 = (const uint4*)WT;
#pragma unroll
    for (int i = 0; i < 8; ++i)
        wtl[i * 512 + tid] = wt4[i * 512 + tid];

    const int wave = tid >> 6;
    const int lane = tid & 63;
    const int m = lane & 15;
    const int quad = lane >> 4;

    __syncthreads();

    for (int stripe = blockIdx.x; stripe < nStripes; stripe += gridDim.x) {
        const int waveBase = stripe * 128 + wave * 16;

        int arow = waveBase + m;
        if (arow >= nNodes) arow = nNodes - 1;       // clamp loads; stores guarded below
        const uint4* hrow = (const uint4*)(HB + (size_t)arow * FEATS);
        const uint4* mrow = (const uint4*)(MB + (size_t)arow * FEATS);

        Frag a[8];
#pragma unroll
        for (int ks = 0; ks < 4; ++ks) a[ks].u = hrow[ks * 4 + quad];
#pragma unroll
        for (int ks = 0; ks < 4; ++ks) a[ks + 4].u = mrow[ks * 4 + quad];

        f32x4 acc[8];
#pragma unroll
        for (int nt = 0; nt < 8; ++nt) acc[nt] = (f32x4){0.f, 0.f, 0.f, 0.f};

#pragma unroll
        for (int ks = 0; ks < 8; ++ks) {
#pragma unroll
            for (int nt = 0; nt < 8; ++nt) {
                Frag b;
                b.u = wtl[(nt * 8 + ks) * 64 + lane];
                acc[nt] = __builtin_amdgcn_mfma_f32_16x16x32_bf16(a[ks].v, b.v, acc[nt], 0, 0, 0);
            }
        }

#pragma unroll
        for (int nt = 0; nt < 8; ++nt) {
            const int col = nt * 16 + m;
            const float bv = bias[col];
#pragma unroll
            for (int r = 0; r < 4; ++r) {
                const int grow = waveBase + quad * 4 + r;   // C/D: row=(lane>>4)*4+reg, col=lane&15
                if (grow >= nNodes) continue;
                float v = acc[nt][r] + bv;
                if (mode) {
                    v = v > 0.f ? v : 0.2f * v;
                    ((unsigned short*)OUTP)[(size_t)grow * FEATS + col] = f32_to_bf16_bits(v);
                } else {
                    ((float*)OUTP)[(size_t)grow * FEATS + col] = v;
                }
            }
        }
    }
}

extern "C" void kernel_launch(void* const* d_in, const int* in_sizes, int n_in,
                              void* d_out, int out_size, void* d_ws, size_t ws_size,
                              hipStream_t stream) {
    const float* emb = (const float*)d_in[0];
    const float* W1s = (const float*)d_in[1];
    const float* W1n = (const float*)d_in[2];
    const float* b1  = (const float*)d_in[3];
    const float* W2s = (const float*)d_in[4];
    const float* W2n = (const float*)d_in[5];
    const float* b2  = (const float*)d_in[6];
    const int*   edg = (const int*)d_in[7];

    const int nE = in_sizes[7] / 2;
    const int* src = edg;
    const int* dst = edg + nE;

    const int chunk = (nE + PB - 1) / PB;            // 6250
    const int nActB = (N_NODES_C + (1 << SH) - 1) >> SH;   // 98
    const int n4 = N_NODES_C * FEATS / 4;            // 3,200,000

    const size_t bfTab = (size_t)N_NODES_C * FEATS * sizeof(unsigned short);  // 25.6 MB

    char* ws = (char*)d_ws;
    int* off      = (int*)(ws);                      // 400 KB + 4
    int* gHist    = (int*)(ws + (512 << 10));        // 128 KB
    int* bstart   = (int*)(ws + (768 << 10));        // 512 B (128+1 bucket bounds)
    int* csr      = (int*)(ws + (1 << 20));          // 6.4 MB
    uint32* ebuf  = (uint32*)(ws + (8 << 20));       // 6.4 MB
    unsigned short* wt1 = (unsigned short*)(ws + (15 << 20));   // 64 KB
    unsigned short* wt2 = (unsigned short*)(ws + (15 << 20) + (64 << 10));
    unsigned short* hb0 = (unsigned short*)(ws + (16 << 20));   // 25.6 MB
    unsigned short* h1b = (unsigned short*)((char*)hb0 + bfTab);
    unsigned short* mnb = (unsigned short*)((char*)h1b + bfTab);
    float* out = (float*)d_out;

    // ---- 1: fused prep (bucket histogram + weight swizzle + bf16 cast) ----
    prep_fused<<<PB + 32 + CAST_BLOCKS, 256, 0, stream>>>(
        dst, gHist, nE, chunk, (const float4*)emb, hb0, n4,
        W1s, W1n, wt1, W2s, W2n, wt2);

    // ---- 2-3: CSR build (fused scan+scatter, then per-bucket finalize) ----
    part_scatter<<<PB, 1024, 0, stream>>>(src, dst, gHist, bstart, ebuf, nE, chunk);
    bucket_csr<<<nActB, 1024, 0, stream>>>(ebuf, bstart, off, csr, nE);

    // ---- 4-7: layers (separate gather + gemm) ----
    const int gatherBlocks = (N_NODES_C + 3) / 4;    // 25000
    const int nStripes = (N_NODES_C + 127) / 128;    // 782
    const int gemmBlocks = 512;                      // persistent: 2 blocks/CU

    gather_mean_w2<<<gatherBlocks, 256, 0, stream>>>(hb0, csr, off, mnb, N_NODES_C);
    sage_gemm_mfma<<<gemmBlocks, 512, 0, stream>>>(hb0, mnb, wt1, b1, h1b, N_NODES_C, nStripes, 1);

    gather_mean_w2<<<gatherBlocks, 256, 0, stream>>>(h1b, csr, off, mnb, N_NODES_C);
    sage_gemm_mfma<<<gemmBlocks, 512, 0, stream>>>(h1b, mnb, wt2, b2, out, N_NODES_C, nStripes, 0);
}

// Round 13
// 319.346 us; speedup vs baseline: 1.1939x; 1.1939x over previous
//
// GraphSAGE MI355X — R13 (R9 GEMM + fused scan/scatter CSR; resubmit, hash-break v3)
#include <hip/hip_runtime.h>
#include <hip/hip_bf16.h>

#define N_NODES_C 100000
#define FEATS 128
#define SH 10             // bucket shift: 1024 nodes per bucket (R8: SH=9 was -12us worse)
#define NBK 128           // padded bucket count (active: 98)
#define PB  256           // partition blocks
#define CAST_BLOCKS 12500 // (100000*128/4)/256

typedef unsigned int uint32;
typedef __bf16 bf16_t;
typedef bf16_t bf16x8 __attribute__((ext_vector_type(8)));
typedef float f32x4 __attribute__((ext_vector_type(4)));

union Frag { uint4 u; bf16x8 v; };

__device__ __forceinline__ unsigned short f32_to_bf16_bits(float f) {
    uint32 u = __float_as_uint(f);
    u += 0x7fffu + ((u >> 16) & 1u);   // round-to-nearest-even (finite values)
    return (unsigned short)(u >> 16);
}
__device__ __forceinline__ float bf16_lo(uint32 p) { return __uint_as_float(p << 16); }
__device__ __forceinline__ float bf16_hi(uint32 p) { return __uint_as_float(p & 0xffff0000u); }

// ---------------- Fused prep: part_count + wtprep x2 + cast ----------------
__global__ __launch_bounds__(256) void prep_fused(
    const int* __restrict__ dst, int* __restrict__ gHist, int nE, int chunk,
    const float4* __restrict__ emb4, unsigned short* __restrict__ hb0, int n4,
    const float* __restrict__ W1s, const float* __restrict__ W1n, unsigned short* __restrict__ wt1,
    const float* __restrict__ W2s, const float* __restrict__ W2n, unsigned short* __restrict__ wt2)
{
    __shared__ int h[NBK];
    const int b = blockIdx.x;
    const int tid = threadIdx.x;

    if (b < PB) {
        // --- bucket histogram over this block's edge chunk ---
        if (tid < NBK) h[tid] = 0;
        __syncthreads();
        const int b0 = b * chunk;
        const int e1 = min(b0 + chunk, nE);
        for (int e = b0 + tid; e < e1; e += 256)
            atomicAdd(&h[dst[e] >> SH], 1);
        __syncthreads();
        if (tid < NBK) gHist[tid * PB + b] = h[tid];
    } else if (b < PB + 32) {
        // --- weight pre-swizzle into B-fragment order ---
        // wt[(f*64+l)*8+j] = W[k][n], f=nt*8+ks, n=nt*16+(l&15), k=ks*32+(l>>4)*8+j
        const int which = (b - PB) >> 4;                 // 0 -> layer1, 1 -> layer2
        const float* Ws = which ? W2s : W1s;
        const float* Wn = which ? W2n : W1n;
        unsigned short* wt = which ? wt2 : wt1;
        int gid = ((b - PB) & 15) * 256 + tid;           // 0..4095
        int frag = gid >> 6, lane = gid & 63;
        int nt = frag >> 3, ks = frag & 7;
        int n = nt * 16 + (lane & 15);
        int kbase = ks * 32 + (lane >> 4) * 8;
        union { unsigned short s[8]; uint4 u; } o;
#pragma unroll
        for (int j = 0; j < 8; ++j) {
            int k = kbase + j;
            float v = (k < 128) ? Ws[(size_t)k * FEATS + n] : Wn[(size_t)(k - 128) * FEATS + n];
            o.s[j] = f32_to_bf16_bits(v);
        }
        *(uint4*)(wt + (size_t)gid * 8) = o.u;
    } else {
        // --- fp32 -> bf16 node-table cast (row-major [N][128]) ---
        int i = (b - PB - 32) * 256 + tid;
        if (i >= n4) return;
        float4 v = emb4[i];
        union { unsigned short s[4]; uint2 u; } o;
        o.s[0] = f32_to_bf16_bits(v.x);
        o.s[1] = f32_to_bf16_bits(v.y);
        o.s[2] = f32_to_bf16_bits(v.z);
        o.s[3] = f32_to_bf16_bits(v.w);
        *(uint2*)(hb0 + (size_t)i * 4) = o.u;
    }
}

// ---------------- P2: fused scan + scatter ----------------
// Every block redundantly computes the exclusive scan of gHist[32768] with the
// proven register-resident 32/thread shape (R7: runtime-loop scans are the trap,
// unrolled register scans are fine), extracts its own 128 bucket cursors via a
// statically-unrolled conditional (no dynamic reg indexing), then scatters.
// Block 0 additionally publishes bucket-boundary offsets bstart[k] for bucket_csr.
// Removes the scan_one dispatch + gap (R10 decomposition: ~-12us).
// LDS cursors only — global per-node cursors were a 250 us disaster (R7: cross-XCD
// atomic line migration + random 4-B scatter write amplification).
__global__ __launch_bounds__(1024) void part_scatter(const int* __restrict__ src,
                                                     const int* __restrict__ dst,
                                                     const int* __restrict__ gHist,
                                                     int* __restrict__ bstart,
                                                     uint32* __restrict__ ebuf,
                                                     int nE, int chunk) {
    __shared__ int ss[1024];
    __shared__ int cur[NBK];
    const int tid = threadIdx.x;
    const int base = tid * 32;
    int pref[32];
    {
        int sum = 0;
#pragma unroll
        for (int j = 0; j < 32; ++j) {
            int v = gHist[base + j];
            pref[j] = sum;
            sum += v;
        }
        ss[tid] = sum;
        __syncthreads();
        for (int d = 1; d < 1024; d <<= 1) {
            int t = (tid >= d) ? ss[tid - d] : 0;
            __syncthreads();
            ss[tid] += t;
            __syncthreads();
        }
        const int ex = ss[tid] - sum;
        // flat index f = k*PB + b (bucket-major). This block needs the scanned
        // value at f with (f & (PB-1)) == blockIdx.x, giving cursor for bucket f>>8.
#pragma unroll
        for (int j = 0; j < 32; ++j) {
            const int f = base + j;
            const int v = ex + pref[j];
            if ((f & (PB - 1)) == blockIdx.x) cur[f >> 8] = v;
        }
        if (blockIdx.x == 0) {
#pragma unroll
            for (int j = 0; j < 32; ++j) {
                const int f = base + j;
                if ((f & (PB - 1)) == 0) bstart[f >> 8] = ex + pref[j];
            }
        }
    }
    __syncthreads();
    const int b0 = blockIdx.x * chunk;
    const int e1 = min(b0 + chunk, nE);
    for (int e = b0 + tid; e < e1; e += 1024) {
        int d = dst[e];
        int pos = atomicAdd(&cur[d >> SH], 1);
        ebuf[pos] = (uint32)src[e] | ((uint32)(d & ((1 << SH) - 1)) << 17);
    }
}

// ---------------- P3: per-bucket CSR finalize ----------------
// csr stores src*256 = byte offset of the node's 256-B feature row (src < 2^17, fits 25 bits).
// SH=10: 98 blocks, full-width 1024-thread LDS scans (R8: SH=9's guarded scans were slower).
__global__ __launch_bounds__(1024) void bucket_csr(const uint32* __restrict__ ebuf,
                                                   const int* __restrict__ bstart,
                                                   int* __restrict__ off,
                                                   int* __restrict__ csr,
                                                   int nE) {
    __shared__ int cnt[1 << SH];
    __shared__ int ss[1 << SH];
    const int b = blockIdx.x;
    const int tid = threadIdx.x;
    const int start = bstart[b];
    const int end = bstart[b + 1];
    const int nodeBase = b << SH;
    cnt[tid] = 0;
    __syncthreads();
    for (int e = start + tid; e < end; e += 1024)
        atomicAdd(&cnt[ebuf[e] >> 17], 1);
    __syncthreads();
    int own = cnt[tid];
    ss[tid] = own;
    __syncthreads();
    for (int d = 1; d < 1024; d <<= 1) {
        int t = (tid >= d) ? ss[tid - d] : 0;
        __syncthreads();
        ss[tid] += t;
        __syncthreads();
    }
    int ex = ss[tid] - own;
    cnt[tid] = ex;                     // becomes placement cursor
    int node = nodeBase + tid;
    if (node < N_NODES_C) off[node] = start + ex;
    if (b == gridDim.x - 1 && tid == 0) off[N_NODES_C] = nE;
    __syncthreads();
    for (int e = start + tid; e < end; e += 1024) {
        uint32 p = ebuf[e];
        int pos = atomicAdd(&cnt[p >> 17], 1);
        csr[start + pos] = (int)((p & 0x1FFFFu) << 8);   // byte offset of src row
    }
}

// ---------------- Gather (mean aggregation over bf16 table) ----------------
// 4 nodes per 256-thread block; one wave per node; uint2 (8 B) per lane so one
// load instruction covers TWO edges' 256-B rows (lanes 0-31 = even edge,
// 32-63 = odd edge). Even/odd partials combined with shfl_xor(32) at the end.
// csr holds byte offsets (src*256): per-load address = one 64-bit add.
// PLATEAU NOTE (R3/R5/R6/R8): uint2x8, uint2x16, uint4x32 variants all land at
// 55-59 us with FETCH pinned at the 181 MB compulsory floor -> this kernel is
// at the random-256B-row memory-system ceiling (~3.8 TB/s effective). uint2x16
// is the best measured (55.5). Do not re-fuse with GEMM (earlier regression).
__global__ __launch_bounds__(256) void gather_mean_w2(const unsigned short* __restrict__ hb,
                                                      const int* __restrict__ csrB,
                                                      const int* __restrict__ off,
                                                      unsigned short* __restrict__ meanb,
                                                      int nNodes) {
    const int node = blockIdx.x * 4 + (threadIdx.x >> 6);
    const int lane = threadIdx.x & 63;
    if (node >= nNodes) return;
    const int start = __builtin_amdgcn_readfirstlane(off[node]);
    const int end   = __builtin_amdgcn_readfirstlane(off[node + 1]);
    const int half = lane >> 5;                 // which edge of a pair
    const int c = lane & 31;                    // uint2 column within 256-B row
    const char* base = (const char*)hb + (size_t)(c * 8);
    float a0 = 0.f, a1 = 0.f, a2 = 0.f, a3 = 0.f;
    int e = start;
    for (; e + 16 <= end; e += 16) {
        const int o0  = csrB[e + 0],  o1  = csrB[e + 1],  o2  = csrB[e + 2],  o3  = csrB[e + 3];
        const int o4  = csrB[e + 4],  o5  = csrB[e + 5],  o6  = csrB[e + 6],  o7  = csrB[e + 7];
        const int o8  = csrB[e + 8],  o9  = csrB[e + 9],  o10 = csrB[e + 10], o11 = csrB[e + 11];
        const int o12 = csrB[e + 12], o13 = csrB[e + 13], o14 = csrB[e + 14], o15 = csrB[e + 15];
        const uint2 u0 = *(const uint2*)(base + (size_t)(half ? o1  : o0));
        const uint2 u1 = *(const uint2*)(base + (size_t)(half ? o3  : o2));
        const uint2 u2 = *(const uint2*)(base + (size_t)(half ? o5  : o4));
        const uint2 u3 = *(const uint2*)(base + (size_t)(half ? o7  : o6));
        const uint2 u4 = *(const uint2*)(base + (size_t)(half ? o9  : o8));
        const uint2 u5 = *(const uint2*)(base + (size_t)(half ? o11 : o10));
        const uint2 u6 = *(const uint2*)(base + (size_t)(half ? o13 : o12));
        const uint2 u7 = *(const uint2*)(base + (size_t)(half ? o15 : o14));
        a0 += bf16_lo(u0.x); a1 += bf16_hi(u0.x); a2 += bf16_lo(u0.y); a3 += bf16_hi(u0.y);
        a0 += bf16_lo(u1.x); a1 += bf16_hi(u1.x); a2 += bf16_lo(u1.y); a3 += bf16_hi(u1.y);
        a0 += bf16_lo(u2.x); a1 += bf16_hi(u2.x); a2 += bf16_lo(u2.y); a3 += bf16_hi(u2.y);
        a0 += bf16_lo(u3.x); a1 += bf16_hi(u3.x); a2 += bf16_lo(u3.y); a3 += bf16_hi(u3.y);
        a0 += bf16_lo(u4.x); a1 += bf16_hi(u4.x); a2 += bf16_lo(u4.y); a3 += bf16_hi(u4.y);
        a0 += bf16_lo(u5.x); a1 += bf16_hi(u5.x); a2 += bf16_lo(u5.y); a3 += bf16_hi(u5.y);
        a0 += bf16_lo(u6.x); a1 += bf16_hi(u6.x); a2 += bf16_lo(u6.y); a3 += bf16_hi(u6.y);
        a0 += bf16_lo(u7.x); a1 += bf16_hi(u7.x); a2 += bf16_lo(u7.y); a3 += bf16_hi(u7.y);
    }
    if (e + 8 <= end) {
        const int o0 = csrB[e + 0], o1 = csrB[e + 1], o2 = csrB[e + 2], o3 = csrB[e + 3];
        const int o4 = csrB[e + 4], o5 = csrB[e + 5], o6 = csrB[e + 6], o7 = csrB[e + 7];
        const uint2 u0 = *(const uint2*)(base + (size_t)(half ? o1 : o0));
        const uint2 u1 = *(const uint2*)(base + (size_t)(half ? o3 : o2));
        const uint2 u2 = *(const uint2*)(base + (size_t)(half ? o5 : o4));
        const uint2 u3 = *(const uint2*)(base + (size_t)(half ? o7 : o6));
        a0 += bf16_lo(u0.x); a1 += bf16_hi(u0.x); a2 += bf16_lo(u0.y); a3 += bf16_hi(u0.y);
        a0 += bf16_lo(u1.x); a1 += bf16_hi(u1.x); a2 += bf16_lo(u1.y); a3 += bf16_hi(u1.y);
        a0 += bf16_lo(u2.x); a1 += bf16_hi(u2.x); a2 += bf16_lo(u2.y); a3 += bf16_hi(u2.y);
        a0 += bf16_lo(u3.x); a1 += bf16_hi(u3.x); a2 += bf16_lo(u3.y); a3 += bf16_hi(u3.y);
        e += 8;
    }
    if (e + 4 <= end) {
        const int o0 = csrB[e + 0], o1 = csrB[e + 1], o2 = csrB[e + 2], o3 = csrB[e + 3];
        const uint2 u0 = *(const uint2*)(base + (size_t)(half ? o1 : o0));
        const uint2 u1 = *(const uint2*)(base + (size_t)(half ? o3 : o2));
        a0 += bf16_lo(u0.x); a1 += bf16_hi(u0.x); a2 += bf16_lo(u0.y); a3 += bf16_hi(u0.y);
        a0 += bf16_lo(u1.x); a1 += bf16_hi(u1.x); a2 += bf16_lo(u1.y); a3 += bf16_hi(u1.y);
        e += 4;
    }
    if (e + 2 <= end) {
        const int o0 = csrB[e + 0], o1 = csrB[e + 1];
        const uint2 u = *(const uint2*)(base + (size_t)(half ? o1 : o0));
        a0 += bf16_lo(u.x); a1 += bf16_hi(u.x); a2 += bf16_lo(u.y); a3 += bf16_hi(u.y);
        e += 2;
    }
    if (e < end && half == 0) {
        const uint2 u = *(const uint2*)(base + (size_t)csrB[e]);
        a0 += bf16_lo(u.x); a1 += bf16_hi(u.x); a2 += bf16_lo(u.y); a3 += bf16_hi(u.y);
    }
    // combine even-edge / odd-edge partial sums held in lane pairs (l, l^32)
    a0 += __shfl_xor(a0, 32);
    a1 += __shfl_xor(a1, 32);
    a2 += __shfl_xor(a2, 32);
    a3 += __shfl_xor(a3, 32);
    const int deg = end - start;
    const float invd = (deg > 0) ? (1.f / (float)deg) : 0.f;
    if (half == 0) {
        uint2 o;
        o.x = ((uint32)f32_to_bf16_bits(a1 * invd) << 16) | (uint32)f32_to_bf16_bits(a0 * invd);
        o.y = ((uint32)f32_to_bf16_bits(a3 * invd) << 16) | (uint32)f32_to_bf16_bits(a2 * invd);
        ((uint2*)meanb)[(size_t)node * 32 + c] = o;
    }
}

// ---------------- MFMA SAGE GEMM (LDS-staged weights, per-stripe blocks) ----------------
// 782 blocks x 512 threads = 8 waves x 16-row stripes (128 rows/block).
// WT (64 KB) staged in LDS once per block; B-frag reads via ds_read_b128.
// NOTE (R4): 32-row/wave (a[16]+acc[16] live) blew the register budget -> scratch
// -> 2x slower. NOTE (R10): persistent-block grid-stride version phase-locked the
// resident waves (all load, then all MFMA) and lost inter-block pipelining ->
// 25 -> 61 us. Short-lived per-stripe blocks ARE the pipeline. Keep this shape.
__global__ __launch_bounds__(512) void sage_gemm_mfma(const unsigned short* __restrict__ HB,
                                                      const unsigned short* __restrict__ MB,
                                                      const unsigned short* __restrict__ WT,
                                                      const float* __restrict__ bias,
                                                      void* __restrict__ OUTP,
                                                      int nNodes, int mode) {
    __shared__ uint4 wtl[4096];                       // 64 KB
    const int tid = threadIdx.x;
    const uint4* wt4 = (const uint4*)WT;
#pragma unroll
    for (int i = 0; i < 8; ++i)
        wtl[i * 512 + tid] = wt4[i * 512 + tid];

    const int wave = tid >> 6;
    const int lane = tid & 63;
    const int waveBase = blockIdx.x * 128 + wave * 16;
    const int m = lane & 15;
    const int quad = lane >> 4;

    int arow = waveBase + m;
    if (arow >= nNodes) arow = nNodes - 1;           // clamp loads; stores guarded below
    const uint4* hrow = (const uint4*)(HB + (size_t)arow * FEATS);
    const uint4* mrow = (const uint4*)(MB + (size_t)arow * FEATS);

    Frag a[8];
#pragma unroll
    for (int ks = 0; ks < 4; ++ks) a[ks].u = hrow[ks * 4 + quad];
#pragma unroll
    for (int ks = 0; ks < 4; ++ks) a[ks + 4].u = mrow[ks * 4 + quad];

    __syncthreads();

    f32x4 acc[8];
#pragma unroll
    for (int nt = 0; nt < 8; ++nt) acc[nt] = (f32x4){0.f, 0.f, 0.f, 0.f};

#pragma unroll
    for (int ks = 0; ks < 8; ++ks) {
#pragma unroll
        for (int nt = 0; nt < 8; ++nt) {
            Frag b;
            b.u = wtl[(nt * 8 + ks) * 64 + lane];
            acc[nt] = __builtin_amdgcn_mfma_f32_16x16x32_bf16(a[ks].v, b.v, acc[nt], 0, 0, 0);
        }
    }

#pragma unroll
    for (int nt = 0; nt < 8; ++nt) {
        const int col = nt * 16 + m;
        const float bv = bias[col];
#pragma unroll
        for (int r = 0; r < 4; ++r) {
            const int grow = waveBase + quad * 4 + r;   // C/D: row=(lane>>4)*4+reg, col=lane&15
            if (grow >= nNodes) continue;
            float v = acc[nt][r] + bv;
            if (mode) {
                v = v > 0.f ? v : 0.2f * v;
                ((unsigned short*)OUTP)[(size_t)grow * FEATS + col] = f32_to_bf16_bits(v);
            } else {
                ((float*)OUTP)[(size_t)grow * FEATS + col] = v;
            }
        }
    }
}

extern "C" void kernel_launch(void* const* d_in, const int* in_sizes, int n_in,
                              void* d_out, int out_size, void* d_ws, size_t ws_size,
                              hipStream_t stream) {
    const float* emb = (const float*)d_in[0];
    const float* W1s = (const float*)d_in[1];
    const float* W1n = (const float*)d_in[2];
    const float* b1  = (const float*)d_in[3];
    const float* W2s = (const float*)d_in[4];
    const float* W2n = (const float*)d_in[5];
    const float* b2  = (const float*)d_in[6];
    const int*   edg = (const int*)d_in[7];

    const int nE = in_sizes[7] / 2;
    const int* src = edg;
    const int* dst = edg + nE;

    const int chunk = (nE + PB - 1) / PB;            // 6250
    const int nActB = (N_NODES_C + (1 << SH) - 1) >> SH;   // 98
    const int n4 = N_NODES_C * FEATS / 4;            // 3,200,000

    const size_t bfTab = (size_t)N_NODES_C * FEATS * sizeof(unsigned short);  // 25.6 MB

    char* ws = (char*)d_ws;
    int* off      = (int*)(ws);                      // 400 KB + 4
    int* gHist    = (int*)(ws + (512 << 10));        // 128 KB
    int* bstart   = (int*)(ws + (768 << 10));        // 512 B (128+1 bucket bounds)
    int* csr      = (int*)(ws + (1 << 20));          // 6.4 MB
    uint32* ebuf  = (uint32*)(ws + (8 << 20));       // 6.4 MB
    unsigned short* wt1 = (unsigned short*)(ws + (15 << 20));   // 64 KB
    unsigned short* wt2 = (unsigned short*)(ws + (15 << 20) + (64 << 10));
    unsigned short* hb0 = (unsigned short*)(ws + (16 << 20));   // 25.6 MB
    unsigned short* h1b = (unsigned short*)((char*)hb0 + bfTab);
    unsigned short* mnb = (unsigned short*)((char*)h1b + bfTab);
    float* out = (float*)d_out;

    // ---- 1: fused prep (bucket histogram + weight swizzle + bf16 cast) ----
    prep_fused<<<PB + 32 + CAST_BLOCKS, 256, 0, stream>>>(
        dst, gHist, nE, chunk, (const float4*)emb, hb0, n4,
        W1s, W1n, wt1, W2s, W2n, wt2);

    // ---- 2-3: CSR build (fused scan+scatter, then per-bucket finalize) ----
    part_scatter<<<PB, 1024, 0, stream>>>(src, dst, gHist, bstart, ebuf, nE, chunk);
    bucket_csr<<<nActB, 1024, 0, stream>>>(ebuf, bstart, off, csr, nE);

    // ---- 4-7: layers (separate gather + gemm) ----
    const int gatherBlocks = (N_NODES_C + 3) / 4;    // 25000
    const int gemmBlocks = (N_NODES_C + 127) / 128;  // 782

    gather_mean_w2<<<gatherBlocks, 256, 0, stream>>>(hb0, csr, off, mnb, N_NODES_C);
    sage_gemm_mfma<<<gemmBlocks, 512, 0, stream>>>(hb0, mnb, wt1, b1, h1b, N_NODES_C, 1);

    gather_mean_w2<<<gatherBlocks, 256, 0, stream>>>(h1b, csr, off, mnb, N_NODES_C);
    sage_gemm_mfma<<<gemmBlocks, 512, 0, stream>>>(h1b, mnb, wt2, b2, out, N_NODES_C, 0);
}

// Round 14
// 316.396 us; speedup vs baseline: 1.2050x; 1.0093x over previous
//
// GraphSAGE MI355X — R14: shfl-based scans (barriers 22->3 / 24->5 in CSR build)
#include <hip/hip_runtime.h>
#include <hip/hip_bf16.h>

#define N_NODES_C 100000
#define FEATS 128
#define SH 10             // bucket shift: 1024 nodes per bucket (R8: SH=9 was -12us worse)
#define NBK 128           // padded bucket count (active: 98)
#define PB  256           // partition blocks
#define CAST_BLOCKS 12500 // (100000*128/4)/256

typedef unsigned int uint32;
typedef __bf16 bf16_t;
typedef bf16_t bf16x8 __attribute__((ext_vector_type(8)));
typedef float f32x4 __attribute__((ext_vector_type(4)));

union Frag { uint4 u; bf16x8 v; };

__device__ __forceinline__ unsigned short f32_to_bf16_bits(float f) {
    uint32 u = __float_as_uint(f);
    u += 0x7fffu + ((u >> 16) & 1u);   // round-to-nearest-even (finite values)
    return (unsigned short)(u >> 16);
}
__device__ __forceinline__ float bf16_lo(uint32 p) { return __uint_as_float(p << 16); }
__device__ __forceinline__ float bf16_hi(uint32 p) { return __uint_as_float(p & 0xffff0000u); }

// ---------------- Fused prep: part_count + wtprep x2 + cast ----------------
__global__ __launch_bounds__(256) void prep_fused(
    const int* __restrict__ dst, int* __restrict__ gHist, int nE, int chunk,
    const float4* __restrict__ emb4, unsigned short* __restrict__ hb0, int n4,
    const float* __restrict__ W1s, const float* __restrict__ W1n, unsigned short* __restrict__ wt1,
    const float* __restrict__ W2s, const float* __restrict__ W2n, unsigned short* __restrict__ wt2)
{
    __shared__ int h[NBK];
    const int b = blockIdx.x;
    const int tid = threadIdx.x;

    if (b < PB) {
        // --- bucket histogram over this block's edge chunk ---
        if (tid < NBK) h[tid] = 0;
        __syncthreads();
        const int b0 = b * chunk;
        const int e1 = min(b0 + chunk, nE);
        for (int e = b0 + tid; e < e1; e += 256)
            atomicAdd(&h[dst[e] >> SH], 1);
        __syncthreads();
        if (tid < NBK) gHist[tid * PB + b] = h[tid];
    } else if (b < PB + 32) {
        // --- weight pre-swizzle into B-fragment order ---
        // wt[(f*64+l)*8+j] = W[k][n], f=nt*8+ks, n=nt*16+(l&15), k=ks*32+(l>>4)*8+j
        const int which = (b - PB) >> 4;                 // 0 -> layer1, 1 -> layer2
        const float* Ws = which ? W2s : W1s;
        const float* Wn = which ? W2n : W1n;
        unsigned short* wt = which ? wt2 : wt1;
        int gid = ((b - PB) & 15) * 256 + tid;           // 0..4095
        int frag = gid >> 6, lane = gid & 63;
        int nt = frag >> 3, ks = frag & 7;
        int n = nt * 16 + (lane & 15);
        int kbase = ks * 32 + (lane >> 4) * 8;
        union { unsigned short s[8]; uint4 u; } o;
#pragma unroll
        for (int j = 0; j < 8; ++j) {
            int k = kbase + j;
            float v = (k < 128) ? Ws[(size_t)k * FEATS + n] : Wn[(size_t)(k - 128) * FEATS + n];
            o.s[j] = f32_to_bf16_bits(v);
        }
        *(uint4*)(wt + (size_t)gid * 8) = o.u;
    } else {
        // --- fp32 -> bf16 node-table cast (row-major [N][128]) ---
        int i = (b - PB - 32) * 256 + tid;
        if (i >= n4) return;
        float4 v = emb4[i];
        union { unsigned short s[4]; uint2 u; } o;
        o.s[0] = f32_to_bf16_bits(v.x);
        o.s[1] = f32_to_bf16_bits(v.y);
        o.s[2] = f32_to_bf16_bits(v.z);
        o.s[3] = f32_to_bf16_bits(v.w);
        *(uint2*)(hb0 + (size_t)i * 4) = o.u;
    }
}

// ---------------- P2: fused scan + scatter (shfl-based scan, 3 barriers) ----------------
// Every block redundantly computes the exclusive scan of gHist[32768]: serial
// register batch (32/thread) -> intra-wave shfl_up scan (no barriers) -> 16
// wave-sums -> wave-0 shfl scan -> wave offsets. Replaces the 1024-wide
// Hillis-Steele (20 barriers in a 16-wave block) with 3 barriers total.
// Block 0 publishes bucket-boundary offsets bstart[k] for bucket_csr.
// LDS cursors only — global per-node cursors were a 250 us disaster (R7: cross-XCD
// atomic line migration + random 4-B scatter write amplification).
__global__ __launch_bounds__(1024) void part_scatter(const int* __restrict__ src,
                                                     const int* __restrict__ dst,
                                                     const int* __restrict__ gHist,
                                                     int* __restrict__ bstart,
                                                     uint32* __restrict__ ebuf,
                                                     int nE, int chunk) {
    __shared__ int wsum[16];
    __shared__ int cur[NBK];
    const int tid = threadIdx.x;
    const int lane = tid & 63;
    const int wid = tid >> 6;
    const int base = tid * 32;
    int pref[32];
    {
        int sum = 0;
#pragma unroll
        for (int j = 0; j < 32; ++j) {
            int v = gHist[base + j];
            pref[j] = sum;
            sum += v;
        }
        // intra-wave inclusive scan of per-thread sums (barrier-free)
        int v = sum;
#pragma unroll
        for (int d = 1; d < 64; d <<= 1) {
            int t = __shfl_up(v, d);
            if (lane >= d) v += t;
        }
        if (lane == 63) wsum[wid] = v;         // wave totals
        __syncthreads();                       // B1
        if (wid == 0) {
            int w = (lane < 16) ? wsum[lane] : 0;
            int winc = w;
#pragma unroll
            for (int d = 1; d < 16; d <<= 1) {
                int t = __shfl_up(winc, d);
                if (lane >= d) winc += t;
            }
            if (lane < 16) wsum[lane] = winc - w;   // exclusive wave offsets
        }
        __syncthreads();                       // B2
        const int ex = (v - sum) + wsum[wid];  // exclusive prefix for this thread
        // flat index f = k*PB + b (bucket-major). This block needs the scanned
        // value at f with (f & (PB-1)) == blockIdx.x, giving cursor for bucket f>>8.
#pragma unroll
        for (int j = 0; j < 32; ++j) {
            const int f = base + j;
            const int v2 = ex + pref[j];
            if ((f & (PB - 1)) == blockIdx.x) cur[f >> 8] = v2;
        }
        if (blockIdx.x == 0) {
#pragma unroll
            for (int j = 0; j < 32; ++j) {
                const int f = base + j;
                if ((f & (PB - 1)) == 0) bstart[f >> 8] = ex + pref[j];
            }
        }
    }
    __syncthreads();                           // B3
    const int b0 = blockIdx.x * chunk;
    const int e1 = min(b0 + chunk, nE);
    for (int e = b0 + tid; e < e1; e += 1024) {
        int d = dst[e];
        int pos = atomicAdd(&cur[d >> SH], 1);
        ebuf[pos] = (uint32)src[e] | ((uint32)(d & ((1 << SH) - 1)) << 17);
    }
}

// ---------------- P3: per-bucket CSR finalize (shfl-based scan, 5 barriers) ----------------
// csr stores src*256 = byte offset of the node's 256-B feature row (src < 2^17, fits 25 bits).
// SH=10: 98 blocks. The 1024-wide counting-sort scan now uses intra-wave shfl_up
// + wave-0 combine (5 barriers total vs 24 Hillis-Steele) — these 98 blocks sit
// on the critical path at 38% CU occupancy, so barrier latency was the cost.
__global__ __launch_bounds__(1024) void bucket_csr(const uint32* __restrict__ ebuf,
                                                   const int* __restrict__ bstart,
                                                   int* __restrict__ off,
                                                   int* __restrict__ csr,
                                                   int nE) {
    __shared__ int cnt[1 << SH];
    __shared__ int wsum[16];
    const int b = blockIdx.x;
    const int tid = threadIdx.x;
    const int lane = tid & 63;
    const int wid = tid >> 6;
    const int start = bstart[b];
    const int end = bstart[b + 1];
    const int nodeBase = b << SH;
    cnt[tid] = 0;
    __syncthreads();                           // B1
    for (int e = start + tid; e < end; e += 1024)
        atomicAdd(&cnt[ebuf[e] >> 17], 1);
    __syncthreads();                           // B2
    const int own = cnt[tid];
    int v = own;
#pragma unroll
    for (int d = 1; d < 64; d <<= 1) {
        int t = __shfl_up(v, d);
        if (lane >= d) v += t;
    }
    if (lane == 63) wsum[wid] = v;
    __syncthreads();                           // B3
    if (wid == 0) {
        int w = (lane < 16) ? wsum[lane] : 0;
        int winc = w;
#pragma unroll
        for (int d = 1; d < 16; d <<= 1) {
            int t = __shfl_up(winc, d);
            if (lane >= d) winc += t;
        }
        if (lane < 16) wsum[lane] = winc - w;  // exclusive wave offsets
    }
    __syncthreads();                           // B4
    const int ex = (v - own) + wsum[wid];
    cnt[tid] = ex;                             // becomes placement cursor
    const int node = nodeBase + tid;
    if (node < N_NODES_C) off[node] = start + ex;
    if (b == gridDim.x - 1 && tid == 0) off[N_NODES_C] = nE;
    __syncthreads();                           // B5
    for (int e = start + tid; e < end; e += 1024) {
        uint32 p = ebuf[e];
        int pos = atomicAdd(&cnt[p >> 17], 1);
        csr[start + pos] = (int)((p & 0x1FFFFu) << 8);   // byte offset of src row
    }
}

// ---------------- Gather (mean aggregation over bf16 table) ----------------
// 4 nodes per 256-thread block; one wave per node; uint2 (8 B) per lane so one
// load instruction covers TWO edges' 256-B rows (lanes 0-31 = even edge,
// 32-63 = odd edge). Even/odd partials combined with shfl_xor(32) at the end.
// csr holds byte offsets (src*256): per-load address = one 64-bit add.
// PLATEAU NOTE (R3/R5/R6/R8): uint2x8, uint2x16, uint4x32 variants all land at
// 55-59 us with FETCH pinned at the 181 MB compulsory floor -> this kernel is
// at the random-256B-row memory-system ceiling (~3.8 TB/s effective). uint2x16
// is the best measured (55.5). Do not re-fuse with GEMM (earlier regression).
__global__ __launch_bounds__(256) void gather_mean_w2(const unsigned short* __restrict__ hb,
                                                      const int* __restrict__ csrB,
                                                      const int* __restrict__ off,
                                                      unsigned short* __restrict__ meanb,
                                                      int nNodes) {
    const int node = blockIdx.x * 4 + (threadIdx.x >> 6);
    const int lane = threadIdx.x & 63;
    if (node >= nNodes) return;
    const int start = __builtin_amdgcn_readfirstlane(off[node]);
    const int end   = __builtin_amdgcn_readfirstlane(off[node + 1]);
    const int half = lane >> 5;                 // which edge of a pair
    const int c = lane & 31;                    // uint2 column within 256-B row
    const char* base = (const char*)hb + (size_t)(c * 8);
    float a0 = 0.f, a1 = 0.f, a2 = 0.f, a3 = 0.f;
    int e = start;
    for (; e + 16 <= end; e += 16) {
        const int o0  = csrB[e + 0],  o1  = csrB[e + 1],  o2  = csrB[e + 2],  o3  = csrB[e + 3];
        const int o4  = csrB[e + 4],  o5  = csrB[e + 5],  o6  = csrB[e + 6],  o7  = csrB[e + 7];
        const int o8  = csrB[e + 8],  o9  = csrB[e + 9],  o10 = csrB[e + 10], o11 = csrB[e + 11];
        const int o12 = csrB[e + 12], o13 = csrB[e + 13], o14 = csrB[e + 14], o15 = csrB[e + 15];
        const uint2 u0 = *(const uint2*)(base + (size_t)(half ? o1  : o0));
        const uint2 u1 = *(const uint2*)(base + (size_t)(half ? o3  : o2));
        const uint2 u2 = *(const uint2*)(base + (size_t)(half ? o5  : o4));
        const uint2 u3 = *(const uint2*)(base + (size_t)(half ? o7  : o6));
        const uint2 u4 = *(const uint2*)(base + (size_t)(half ? o9  : o8));
        const uint2 u5 = *(const uint2*)(base + (size_t)(half ? o11 : o10));
        const uint2 u6 = *(const uint2*)(base + (size_t)(half ? o13 : o12));
        const uint2 u7 = *(const uint2*)(base + (size_t)(half ? o15 : o14));
        a0 += bf16_lo(u0.x); a1 += bf16_hi(u0.x); a2 += bf16_lo(u0.y); a3 += bf16_hi(u0.y);
        a0 += bf16_lo(u1.x); a1 += bf16_hi(u1.x); a2 += bf16_lo(u1.y); a3 += bf16_hi(u1.y);
        a0 += bf16_lo(u2.x); a1 += bf16_hi(u2.x); a2 += bf16_lo(u2.y); a3 += bf16_hi(u2.y);
        a0 += bf16_lo(u3.x); a1 += bf16_hi(u3.x); a2 += bf16_lo(u3.y); a3 += bf16_hi(u3.y);
        a0 += bf16_lo(u4.x); a1 += bf16_hi(u4.x); a2 += bf16_lo(u4.y); a3 += bf16_hi(u4.y);
        a0 += bf16_lo(u5.x); a1 += bf16_hi(u5.x); a2 += bf16_lo(u5.y); a3 += bf16_hi(u5.y);
        a0 += bf16_lo(u6.x); a1 += bf16_hi(u6.x); a2 += bf16_lo(u6.y); a3 += bf16_hi(u6.y);
        a0 += bf16_lo(u7.x); a1 += bf16_hi(u7.x); a2 += bf16_lo(u7.y); a3 += bf16_hi(u7.y);
    }
    if (e + 8 <= end) {
        const int o0 = csrB[e + 0], o1 = csrB[e + 1], o2 = csrB[e + 2], o3 = csrB[e + 3];
        const int o4 = csrB[e + 4], o5 = csrB[e + 5], o6 = csrB[e + 6], o7 = csrB[e + 7];
        const uint2 u0 = *(const uint2*)(base + (size_t)(half ? o1 : o0));
        const uint2 u1 = *(const uint2*)(base + (size_t)(half ? o3 : o2));
        const uint2 u2 = *(const uint2*)(base + (size_t)(half ? o5 : o4));
        const uint2 u3 = *(const uint2*)(base + (size_t)(half ? o7 : o6));
        a0 += bf16_lo(u0.x); a1 += bf16_hi(u0.x); a2 += bf16_lo(u0.y); a3 += bf16_hi(u0.y);
        a0 += bf16_lo(u1.x); a1 += bf16_hi(u1.x); a2 += bf16_lo(u1.y); a3 += bf16_hi(u1.y);
        a0 += bf16_lo(u2.x); a1 += bf16_hi(u2.x); a2 += bf16_lo(u2.y); a3 += bf16_hi(u2.y);
        a0 += bf16_lo(u3.x); a1 += bf16_hi(u3.x); a2 += bf16_lo(u3.y); a3 += bf16_hi(u3.y);
        e += 8;
    }
    if (e + 4 <= end) {
        const int o0 = csrB[e + 0], o1 = csrB[e + 1], o2 = csrB[e + 2], o3 = csrB[e + 3];
        const uint2 u0 = *(const uint2*)(base + (size_t)(half ? o1 : o0));
        const uint2 u1 = *(const uint2*)(base + (size_t)(half ? o3 : o2));
        a0 += bf16_lo(u0.x); a1 += bf16_hi(u0.x); a2 += bf16_lo(u0.y); a3 += bf16_hi(u0.y);
        a0 += bf16_lo(u1.x); a1 += bf16_hi(u1.x); a2 += bf16_lo(u1.y); a3 += bf16_hi(u1.y);
        e += 4;
    }
    if (e + 2 <= end) {
        const int o0 = csrB[e + 0], o1 = csrB[e + 1];
        const uint2 u = *(const uint2*)(base + (size_t)(half ? o1 : o0));
        a0 += bf16_lo(u.x); a1 += bf16_hi(u.x); a2 += bf16_lo(u.y); a3 += bf16_hi(u.y);
        e += 2;
    }
    if (e < end && half == 0) {
        const uint2 u = *(const uint2*)(base + (size_t)csrB[e]);
        a0 += bf16_lo(u.x); a1 += bf16_hi(u.x); a2 += bf16_lo(u.y); a3 += bf16_hi(u.y);
    }
    // combine even-edge / odd-edge partial sums held in lane pairs (l, l^32)
    a0 += __shfl_xor(a0, 32);
    a1 += __shfl_xor(a1, 32);
    a2 += __shfl_xor(a2, 32);
    a3 += __shfl_xor(a3, 32);
    const int deg = end - start;
    const float invd = (deg > 0) ? (1.f / (float)deg) : 0.f;
    if (half == 0) {
        uint2 o;
        o.x = ((uint32)f32_to_bf16_bits(a1 * invd) << 16) | (uint32)f32_to_bf16_bits(a0 * invd);
        o.y = ((uint32)f32_to_bf16_bits(a3 * invd) << 16) | (uint32)f32_to_bf16_bits(a2 * invd);
        ((uint2*)meanb)[(size_t)node * 32 + c] = o;
    }
}

// ---------------- MFMA SAGE GEMM (LDS-staged weights, per-stripe blocks) ----------------
// 782 blocks x 512 threads = 8 waves x 16-row stripes (128 rows/block).
// WT (64 KB) staged in LDS once per block; B-frag reads via ds_read_b128.
// NOTE (R4): 32-row/wave (a[16]+acc[16] live) blew the register budget -> scratch
// -> 2x slower. NOTE (R10): persistent-block grid-stride version phase-locked the
// resident waves (all load, then all MFMA) and lost inter-block pipelining ->
// 25 -> 61 us. Short-lived per-stripe blocks ARE the pipeline. Keep this shape.
__global__ __launch_bounds__(512) void sage_gemm_mfma(const unsigned short* __restrict__ HB,
                                                      const unsigned short* __restrict__ MB,
                                                      const unsigned short* __restrict__ WT,
                                                      const float* __restrict__ bias,
                                                      void* __restrict__ OUTP,
                                                      int nNodes, int mode) {
    __shared__ uint4 wtl[4096];                       // 64 KB
    const int tid = threadIdx.x;
    const uint4* wt4 = (const uint4*)WT;
#pragma unroll
    for (int i = 0; i < 8; ++i)
        wtl[i * 512 + tid] = wt4[i * 512 + tid];

    const int wave = tid >> 6;
    const int lane = tid & 63;
    const int waveBase = blockIdx.x * 128 + wave * 16;
    const int m = lane & 15;
    const int quad = lane >> 4;

    int arow = waveBase + m;
    if (arow >= nNodes) arow = nNodes - 1;           // clamp loads; stores guarded below
    const uint4* hrow = (const uint4*)(HB + (size_t)arow * FEATS);
    const uint4* mrow = (const uint4*)(MB + (size_t)arow * FEATS);

    Frag a[8];
#pragma unroll
    for (int ks = 0; ks < 4; ++ks) a[ks].u = hrow[ks * 4 + quad];
#pragma unroll
    for (int ks = 0; ks < 4; ++ks) a[ks + 4].u = mrow[ks * 4 + quad];

    __syncthreads();

    f32x4 acc[8];
#pragma unroll
    for (int nt = 0; nt < 8; ++nt) acc[nt] = (f32x4){0.f, 0.f, 0.f, 0.f};

#pragma unroll
    for (int ks = 0; ks < 8; ++ks) {
#pragma unroll
        for (int nt = 0; nt < 8; ++nt) {
            Frag b;
            b.u = wtl[(nt * 8 + ks) * 64 + lane];
            acc[nt] = __builtin_amdgcn_mfma_f32_16x16x32_bf16(a[ks].v, b.v, acc[nt], 0, 0, 0);
        }
    }

#pragma unroll
    for (int nt = 0; nt < 8; ++nt) {
        const int col = nt * 16 + m;
        const float bv = bias[col];
#pragma unroll
        for (int r = 0; r < 4; ++r) {
            const int grow = waveBase + quad * 4 + r;   // C/D: row=(lane>>4)*4+reg, col=lane&15
            if (grow >= nNodes) continue;
            float v = acc[nt][r] + bv;
            if (mode) {
                v = v > 0.f ? v : 0.2f * v;
                ((unsigned short*)OUTP)[(size_t)grow * FEATS + col] = f32_to_bf16_bits(v);
            } else {
                ((float*)OUTP)[(size_t)grow * FEATS + col] = v;
            }
        }
    }
}

extern "C" void kernel_launch(void* const* d_in, const int* in_sizes, int n_in,
                              void* d_out, int out_size, void* d_ws, size_t ws_size,
                              hipStream_t stream) {
    const float* emb = (const float*)d_in[0];
    const float* W1s = (const float*)d_in[1];
    const float* W1n = (const float*)d_in[2];
    const float* b1  = (const float*)d_in[3];
    const float* W2s = (const float*)d_in[4];
    const float* W2n = (const float*)d_in[5];
    const float* b2  = (const float*)d_in[6];
    const int*   edg = (const int*)d_in[7];

    const int nE = in_sizes[7] / 2;
    const int* src = edg;
    const int* dst = edg + nE;

    const int chunk = (nE + PB - 1) / PB;            // 6250
    const int nActB = (N_NODES_C + (1 << SH) - 1) >> SH;   // 98
    const int n4 = N_NODES_C * FEATS / 4;            // 3,200,000

    const size_t bfTab = (size_t)N_NODES_C * FEATS * sizeof(unsigned short);  // 25.6 MB

    char* ws = (char*)d_ws;
    int* off      = (int*)(ws);                      // 400 KB + 4
    int* gHist    = (int*)(ws + (512 << 10));        // 128 KB
    int* bstart   = (int*)(ws + (768 << 10));        // 512 B (128+1 bucket bounds)
    int* csr      = (int*)(ws + (1 << 20));          // 6.4 MB
    uint32* ebuf  = (uint32*)(ws + (8 << 20));       // 6.4 MB
    unsigned short* wt1 = (unsigned short*)(ws + (15 << 20));   // 64 KB
    unsigned short* wt2 = (unsigned short*)(ws + (15 << 20) + (64 << 10));
    unsigned short* hb0 = (unsigned short*)(ws + (16 << 20));   // 25.6 MB
    unsigned short* h1b = (unsigned short*)((char*)hb0 + bfTab);
    unsigned short* mnb = (unsigned short*)((char*)h1b + bfTab);
    float* out = (float*)d_out;

    // ---- 1: fused prep (bucket histogram + weight swizzle + bf16 cast) ----
    prep_fused<<<PB + 32 + CAST_BLOCKS, 256, 0, stream>>>(
        dst, gHist, nE, chunk, (const float4*)emb, hb0, n4,
        W1s, W1n, wt1, W2s, W2n, wt2);

    // ---- 2-3: CSR build (fused scan+scatter, then per-bucket finalize) ----
    part_scatter<<<PB, 1024, 0, stream>>>(src, dst, gHist, bstart, ebuf, nE, chunk);
    bucket_csr<<<nActB, 1024, 0, stream>>>(ebuf, bstart, off, csr, nE);

    // ---- 4-7: layers (separate gather + gemm) ----
    const int gatherBlocks = (N_NODES_C + 3) / 4;    // 25000
    const int gemmBlocks = (N_NODES_C + 127) / 128;  // 782

    gather_mean_w2<<<gatherBlocks, 256, 0, stream>>>(hb0, csr, off, mnb, N_NODES_C);
    sage_gemm_mfma<<<gemmBlocks, 512, 0, stream>>>(hb0, mnb, wt1, b1, h1b, N_NODES_C, 1);

    gather_mean_w2<<<gatherBlocks, 256, 0, stream>>>(h1b, csr, off, mnb, N_NODES_C);
    sage_gemm_mfma<<<gemmBlocks, 512, 0, stream>>>(h1b, mnb, wt2, b2, out, N_NODES_C, 0);
}

// Round 15
// 306.973 us; speedup vs baseline: 1.2420x; 1.0307x over previous
//
// GraphSAGE MI355X — R15: MLP unrolls in prep/scatter/csr (batched loads before atomics)
#include <hip/hip_runtime.h>
#include <hip/hip_bf16.h>

#define N_NODES_C 100000
#define FEATS 128
#define SH 10             // bucket shift: 1024 nodes per bucket (R8: SH=9 was -12us worse)
#define NBK 128           // padded bucket count (active: 98)
#define PB  256           // partition blocks
#define CAST_BLOCKS 1563  // (100000*128/4) / (256 threads * 8 float4/thread)

typedef unsigned int uint32;
typedef __bf16 bf16_t;
typedef bf16_t bf16x8 __attribute__((ext_vector_type(8)));
typedef float f32x4 __attribute__((ext_vector_type(4)));

union Frag { uint4 u; bf16x8 v; };

__device__ __forceinline__ unsigned short f32_to_bf16_bits(float f) {
    uint32 u = __float_as_uint(f);
    u += 0x7fffu + ((u >> 16) & 1u);   // round-to-nearest-even (finite values)
    return (unsigned short)(u >> 16);
}
__device__ __forceinline__ float bf16_lo(uint32 p) { return __uint_as_float(p << 16); }
__device__ __forceinline__ float bf16_hi(uint32 p) { return __uint_as_float(p & 0xffff0000u); }

// ---------------- Fused prep: part_count + wtprep x2 + cast ----------------
// R15: cast = 8 float4/thread (8 loads in flight, 8x fewer blocks); histogram
// loop unrolled x4 with loads batched before atomics. Latency-bound loops need
// multiple loads in flight (same lesson as the R3 gather unroll).
__global__ __launch_bounds__(256) void prep_fused(
    const int* __restrict__ dst, int* __restrict__ gHist, int nE, int chunk,
    const float4* __restrict__ emb4, unsigned short* __restrict__ hb0, int n4,
    const float* __restrict__ W1s, const float* __restrict__ W1n, unsigned short* __restrict__ wt1,
    const float* __restrict__ W2s, const float* __restrict__ W2n, unsigned short* __restrict__ wt2)
{
    __shared__ int h[NBK];
    const int b = blockIdx.x;
    const int tid = threadIdx.x;

    if (b < PB) {
        // --- bucket histogram over this block's edge chunk ---
        if (tid < NBK) h[tid] = 0;
        __syncthreads();
        const int b0 = b * chunk;
        const int e1 = min(b0 + chunk, nE);
        int e = b0 + tid;
        for (; e + 768 < e1; e += 1024) {
            const int d0 = dst[e], d1 = dst[e + 256], d2 = dst[e + 512], d3 = dst[e + 768];
            atomicAdd(&h[d0 >> SH], 1);
            atomicAdd(&h[d1 >> SH], 1);
            atomicAdd(&h[d2 >> SH], 1);
            atomicAdd(&h[d3 >> SH], 1);
        }
        for (; e < e1; e += 256)
            atomicAdd(&h[dst[e] >> SH], 1);
        __syncthreads();
        if (tid < NBK) gHist[tid * PB + b] = h[tid];
    } else if (b < PB + 32) {
        // --- weight pre-swizzle into B-fragment order ---
        // wt[(f*64+l)*8+j] = W[k][n], f=nt*8+ks, n=nt*16+(l&15), k=ks*32+(l>>4)*8+j
        const int which = (b - PB) >> 4;                 // 0 -> layer1, 1 -> layer2
        const float* Ws = which ? W2s : W1s;
        const float* Wn = which ? W2n : W1n;
        unsigned short* wt = which ? wt2 : wt1;
        int gid = ((b - PB) & 15) * 256 + tid;           // 0..4095
        int frag = gid >> 6, lane = gid & 63;
        int nt = frag >> 3, ks = frag & 7;
        int n = nt * 16 + (lane & 15);
        int kbase = ks * 32 + (lane >> 4) * 8;
        union { unsigned short s[8]; uint4 u; } o;
#pragma unroll
        for (int j = 0; j < 8; ++j) {
            int k = kbase + j;
            float v = (k < 128) ? Ws[(size_t)k * FEATS + n] : Wn[(size_t)(k - 128) * FEATS + n];
            o.s[j] = f32_to_bf16_bits(v);
        }
        *(uint4*)(wt + (size_t)gid * 8) = o.u;
    } else {
        // --- fp32 -> bf16 node-table cast (row-major [N][128]), 8 float4/thread ---
        const int base0 = (b - PB - 32) * 2048 + tid;
        if (base0 + 7 * 256 < n4) {
            float4 v[8];
#pragma unroll
            for (int r = 0; r < 8; ++r) v[r] = emb4[base0 + r * 256];
#pragma unroll
            for (int r = 0; r < 8; ++r) {
                union { unsigned short s[4]; uint2 u; } o;
                o.s[0] = f32_to_bf16_bits(v[r].x);
                o.s[1] = f32_to_bf16_bits(v[r].y);
                o.s[2] = f32_to_bf16_bits(v[r].z);
                o.s[3] = f32_to_bf16_bits(v[r].w);
                *(uint2*)(hb0 + (size_t)(base0 + r * 256) * 4) = o.u;
            }
        } else {
#pragma unroll
            for (int r = 0; r < 8; ++r) {
                const int i = base0 + r * 256;
                if (i < n4) {
                    float4 v = emb4[i];
                    union { unsigned short s[4]; uint2 u; } o;
                    o.s[0] = f32_to_bf16_bits(v.x);
                    o.s[1] = f32_to_bf16_bits(v.y);
                    o.s[2] = f32_to_bf16_bits(v.z);
                    o.s[3] = f32_to_bf16_bits(v.w);
                    *(uint2*)(hb0 + (size_t)i * 4) = o.u;
                }
            }
        }
    }
}

// ---------------- P2: fused scan + scatter (shfl scan; scatter unrolled x4) ----------------
// Every block redundantly computes the exclusive scan of gHist[32768]: serial
// register batch (32/thread) -> intra-wave shfl_up scan -> wave-0 combine.
// Scatter loop unrolled x4 with dst/src loads batched before the LDS atomics.
// Block 0 publishes bucket-boundary offsets bstart[k] for bucket_csr.
// LDS cursors only — global per-node cursors were a 250 us disaster (R7: cross-XCD
// atomic line migration + random 4-B scatter write amplification).
__global__ __launch_bounds__(1024) void part_scatter(const int* __restrict__ src,
                                                     const int* __restrict__ dst,
                                                     const int* __restrict__ gHist,
                                                     int* __restrict__ bstart,
                                                     uint32* __restrict__ ebuf,
                                                     int nE, int chunk) {
    __shared__ int wsum[16];
    __shared__ int cur[NBK];
    const int tid = threadIdx.x;
    const int lane = tid & 63;
    const int wid = tid >> 6;
    const int base = tid * 32;
    int pref[32];
    {
        int sum = 0;
#pragma unroll
        for (int j = 0; j < 32; ++j) {
            int v = gHist[base + j];
            pref[j] = sum;
            sum += v;
        }
        // intra-wave inclusive scan of per-thread sums (barrier-free)
        int v = sum;
#pragma unroll
        for (int d = 1; d < 64; d <<= 1) {
            int t = __shfl_up(v, d);
            if (lane >= d) v += t;
        }
        if (lane == 63) wsum[wid] = v;         // wave totals
        __syncthreads();                       // B1
        if (wid == 0) {
            int w = (lane < 16) ? wsum[lane] : 0;
            int winc = w;
#pragma unroll
            for (int d = 1; d < 16; d <<= 1) {
                int t = __shfl_up(winc, d);
                if (lane >= d) winc += t;
            }
            if (lane < 16) wsum[lane] = winc - w;   // exclusive wave offsets
        }
        __syncthreads();                       // B2
        const int ex = (v - sum) + wsum[wid];  // exclusive prefix for this thread
        // flat index f = k*PB + b (bucket-major). This block needs the scanned
        // value at f with (f & (PB-1)) == blockIdx.x, giving cursor for bucket f>>8.
#pragma unroll
        for (int j = 0; j < 32; ++j) {
            const int f = base + j;
            const int v2 = ex + pref[j];
            if ((f & (PB - 1)) == blockIdx.x) cur[f >> 8] = v2;
        }
        if (blockIdx.x == 0) {
#pragma unroll
            for (int j = 0; j < 32; ++j) {
                const int f = base + j;
                if ((f & (PB - 1)) == 0) bstart[f >> 8] = ex + pref[j];
            }
        }
    }
    __syncthreads();                           // B3
    const int b0 = blockIdx.x * chunk;
    const int e1 = min(b0 + chunk, nE);
    int e = b0 + tid;
    for (; e + 3072 < e1; e += 4096) {
        const int d0 = dst[e],        d1 = dst[e + 1024], d2 = dst[e + 2048], d3 = dst[e + 3072];
        const int s0 = src[e],        s1 = src[e + 1024], s2 = src[e + 2048], s3 = src[e + 3072];
        const int p0 = atomicAdd(&cur[d0 >> SH], 1);
        ebuf[p0] = (uint32)s0 | ((uint32)(d0 & ((1 << SH) - 1)) << 17);
        const int p1 = atomicAdd(&cur[d1 >> SH], 1);
        ebuf[p1] = (uint32)s1 | ((uint32)(d1 & ((1 << SH) - 1)) << 17);
        const int p2 = atomicAdd(&cur[d2 >> SH], 1);
        ebuf[p2] = (uint32)s2 | ((uint32)(d2 & ((1 << SH) - 1)) << 17);
        const int p3 = atomicAdd(&cur[d3 >> SH], 1);
        ebuf[p3] = (uint32)s3 | ((uint32)(d3 & ((1 << SH) - 1)) << 17);
    }
    for (; e < e1; e += 1024) {
        const int d = dst[e];
        const int pos = atomicAdd(&cur[d >> SH], 1);
        ebuf[pos] = (uint32)src[e] | ((uint32)(d & ((1 << SH) - 1)) << 17);
    }
}

// ---------------- P3: per-bucket CSR finalize (shfl scan; edge loops unrolled x4) ----------------
// csr stores src*256 = byte offset of the node's 256-B feature row (src < 2^17, fits 25 bits).
// SH=10: 98 blocks. Both edge passes unrolled x4 with ebuf loads batched before
// the LDS atomics (4 loads in flight instead of 1 — latency-bound at 38% CU use).
__global__ __launch_bounds__(1024) void bucket_csr(const uint32* __restrict__ ebuf,
                                                   const int* __restrict__ bstart,
                                                   int* __restrict__ off,
                                                   int* __restrict__ csr,
                                                   int nE) {
    __shared__ int cnt[1 << SH];
    __shared__ int wsum[16];
    const int b = blockIdx.x;
    const int tid = threadIdx.x;
    const int lane = tid & 63;
    const int wid = tid >> 6;
    const int start = bstart[b];
    const int end = bstart[b + 1];
    const int nodeBase = b << SH;
    cnt[tid] = 0;
    __syncthreads();                           // B1
    {
        int e = start + tid;
        for (; e + 3072 < end; e += 4096) {
            const uint32 p0 = ebuf[e],        p1 = ebuf[e + 1024];
            const uint32 p2 = ebuf[e + 2048], p3 = ebuf[e + 3072];
            atomicAdd(&cnt[p0 >> 17], 1);
            atomicAdd(&cnt[p1 >> 17], 1);
            atomicAdd(&cnt[p2 >> 17], 1);
            atomicAdd(&cnt[p3 >> 17], 1);
        }
        for (; e < end; e += 1024)
            atomicAdd(&cnt[ebuf[e] >> 17], 1);
    }
    __syncthreads();                           // B2
    const int own = cnt[tid];
    int v = own;
#pragma unroll
    for (int d = 1; d < 64; d <<= 1) {
        int t = __shfl_up(v, d);
        if (lane >= d) v += t;
    }
    if (lane == 63) wsum[wid] = v;
    __syncthreads();                           // B3
    if (wid == 0) {
        int w = (lane < 16) ? wsum[lane] : 0;
        int winc = w;
#pragma unroll
        for (int d = 1; d < 16; d <<= 1) {
            int t = __shfl_up(winc, d);
            if (lane >= d) winc += t;
        }
        if (lane < 16) wsum[lane] = winc - w;  // exclusive wave offsets
    }
    __syncthreads();                           // B4
    const int ex = (v - own) + wsum[wid];
    cnt[tid] = ex;                             // becomes placement cursor
    const int node = nodeBase + tid;
    if (node < N_NODES_C) off[node] = start + ex;
    if (b == gridDim.x - 1 && tid == 0) off[N_NODES_C] = nE;
    __syncthreads();                           // B5
    {
        int e = start + tid;
        for (; e + 3072 < end; e += 4096) {
            const uint32 p0 = ebuf[e],        p1 = ebuf[e + 1024];
            const uint32 p2 = ebuf[e + 2048], p3 = ebuf[e + 3072];
            const int q0 = atomicAdd(&cnt[p0 >> 17], 1);
            csr[start + q0] = (int)((p0 & 0x1FFFFu) << 8);
            const int q1 = atomicAdd(&cnt[p1 >> 17], 1);
            csr[start + q1] = (int)((p1 & 0x1FFFFu) << 8);
            const int q2 = atomicAdd(&cnt[p2 >> 17], 1);
            csr[start + q2] = (int)((p2 & 0x1FFFFu) << 8);
            const int q3 = atomicAdd(&cnt[p3 >> 17], 1);
            csr[start + q3] = (int)((p3 & 0x1FFFFu) << 8);
        }
        for (; e < end; e += 1024) {
            const uint32 p = ebuf[e];
            const int pos = atomicAdd(&cnt[p >> 17], 1);
            csr[start + pos] = (int)((p & 0x1FFFFu) << 8);   // byte offset of src row
        }
    }
}

// ---------------- Gather (mean aggregation over bf16 table) ----------------
// 4 nodes per 256-thread block; one wave per node; uint2 (8 B) per lane so one
// load instruction covers TWO edges' 256-B rows (lanes 0-31 = even edge,
// 32-63 = odd edge). Even/odd partials combined with shfl_xor(32) at the end.
// csr holds byte offsets (src*256): per-load address = one 64-bit add.
// PLATEAU NOTE (R3/R5/R6/R8): uint2x8, uint2x16, uint4x32 variants all land at
// 55-59 us with FETCH pinned at the 181 MB compulsory floor -> this kernel is
// at the random-256B-row memory-system ceiling (~3.8 TB/s effective). uint2x16
// is the best measured (55.5). Do not re-fuse with GEMM (earlier regression).
__global__ __launch_bounds__(256) void gather_mean_w2(const unsigned short* __restrict__ hb,
                                                      const int* __restrict__ csrB,
                                                      const int* __restrict__ off,
                                                      unsigned short* __restrict__ meanb,
                                                      int nNodes) {
    const int node = blockIdx.x * 4 + (threadIdx.x >> 6);
    const int lane = threadIdx.x & 63;
    if (node >= nNodes) return;
    const int start = __builtin_amdgcn_readfirstlane(off[node]);
    const int end   = __builtin_amdgcn_readfirstlane(off[node + 1]);
    const int half = lane >> 5;                 // which edge of a pair
    const int c = lane & 31;                    // uint2 column within 256-B row
    const char* base = (const char*)hb + (size_t)(c * 8);
    float a0 = 0.f, a1 = 0.f, a2 = 0.f, a3 = 0.f;
    int e = start;
    for (; e + 16 <= end; e += 16) {
        const int o0  = csrB[e + 0],  o1  = csrB[e + 1],  o2  = csrB[e + 2],  o3  = csrB[e + 3];
        const int o4  = csrB[e + 4],  o5  = csrB[e + 5],  o6  = csrB[e + 6],  o7  = csrB[e + 7];
        const int o8  = csrB[e + 8],  o9  = csrB[e + 9],  o10 = csrB[e + 10], o11 = csrB[e + 11];
        const int o12 = csrB[e + 12], o13 = csrB[e + 13], o14 = csrB[e + 14], o15 = csrB[e + 15];
        const uint2 u0 = *(const uint2*)(base + (size_t)(half ? o1  : o0));
        const uint2 u1 = *(const uint2*)(base + (size_t)(half ? o3  : o2));
        const uint2 u2 = *(const uint2*)(base + (size_t)(half ? o5  : o4));
        const uint2 u3 = *(const uint2*)(base + (size_t)(half ? o7  : o6));
        const uint2 u4 = *(const uint2*)(base + (size_t)(half ? o9  : o8));
        const uint2 u5 = *(const uint2*)(base + (size_t)(half ? o11 : o10));
        const uint2 u6 = *(const uint2*)(base + (size_t)(half ? o13 : o12));
        const uint2 u7 = *(const uint2*)(base + (size_t)(half ? o15 : o14));
        a0 += bf16_lo(u0.x); a1 += bf16_hi(u0.x); a2 += bf16_lo(u0.y); a3 += bf16_hi(u0.y);
        a0 += bf16_lo(u1.x); a1 += bf16_hi(u1.x); a2 += bf16_lo(u1.y); a3 += bf16_hi(u1.y);
        a0 += bf16_lo(u2.x); a1 += bf16_hi(u2.x); a2 += bf16_lo(u2.y); a3 += bf16_hi(u2.y);
        a0 += bf16_lo(u3.x); a1 += bf16_hi(u3.x); a2 += bf16_lo(u3.y); a3 += bf16_hi(u3.y);
        a0 += bf16_lo(u4.x); a1 += bf16_hi(u4.x); a2 += bf16_lo(u4.y); a3 += bf16_hi(u4.y);
        a0 += bf16_lo(u5.x); a1 += bf16_hi(u5.x); a2 += bf16_lo(u5.y); a3 += bf16_hi(u5.y);
        a0 += bf16_lo(u6.x); a1 += bf16_hi(u6.x); a2 += bf16_lo(u6.y); a3 += bf16_hi(u6.y);
        a0 += bf16_lo(u7.x); a1 += bf16_hi(u7.x); a2 += bf16_lo(u7.y); a3 += bf16_hi(u7.y);
    }
    if (e + 8 <= end) {
        const int o0 = csrB[e + 0], o1 = csrB[e + 1], o2 = csrB[e + 2], o3 = csrB[e + 3];
        const int o4 = csrB[e + 4], o5 = csrB[e + 5], o6 = csrB[e + 6], o7 = csrB[e + 7];
        const uint2 u0 = *(const uint2*)(base + (size_t)(half ? o1 : o0));
        const uint2 u1 = *(const uint2*)(base + (size_t)(half ? o3 : o2));
        const uint2 u2 = *(const uint2*)(base + (size_t)(half ? o5 : o4));
        const uint2 u3 = *(const uint2*)(base + (size_t)(half ? o7 : o6));
        a0 += bf16_lo(u0.x); a1 += bf16_hi(u0.x); a2 += bf16_lo(u0.y); a3 += bf16_hi(u0.y);
        a0 += bf16_lo(u1.x); a1 += bf16_hi(u1.x); a2 += bf16_lo(u1.y); a3 += bf16_hi(u1.y);
        a0 += bf16_lo(u2.x); a1 += bf16_hi(u2.x); a2 += bf16_lo(u2.y); a3 += bf16_hi(u2.y);
        a0 += bf16_lo(u3.x); a1 += bf16_hi(u3.x); a2 += bf16_lo(u3.y); a3 += bf16_hi(u3.y);
        e += 8;
    }
    if (e + 4 <= end) {
        const int o0 = csrB[e + 0], o1 = csrB[e + 1], o2 = csrB[e + 2], o3 = csrB[e + 3];
        const uint2 u0 = *(const uint2*)(base + (size_t)(half ? o1 : o0));
        const uint2 u1 = *(const uint2*)(base + (size_t)(half ? o3 : o2));
        a0 += bf16_lo(u0.x); a1 += bf16_hi(u0.x); a2 += bf16_lo(u0.y); a3 += bf16_hi(u0.y);
        a0 += bf16_lo(u1.x); a1 += bf16_hi(u1.x); a2 += bf16_lo(u1.y); a3 += bf16_hi(u1.y);
        e += 4;
    }
    if (e + 2 <= end) {
        const int o0 = csrB[e + 0], o1 = csrB[e + 1];
        const uint2 u = *(const uint2*)(base + (size_t)(half ? o1 : o0));
        a0 += bf16_lo(u.x); a1 += bf16_hi(u.x); a2 += bf16_lo(u.y); a3 += bf16_hi(u.y);
        e += 2;
    }
    if (e < end && half == 0) {
        const uint2 u = *(const uint2*)(base + (size_t)csrB[e]);
        a0 += bf16_lo(u.x); a1 += bf16_hi(u.x); a2 += bf16_lo(u.y); a3 += bf16_hi(u.y);
    }
    // combine even-edge / odd-edge partial sums held in lane pairs (l, l^32)
    a0 += __shfl_xor(a0, 32);
    a1 += __shfl_xor(a1, 32);
    a2 += __shfl_xor(a2, 32);
    a3 += __shfl_xor(a3, 32);
    const int deg = end - start;
    const float invd = (deg > 0) ? (1.f / (float)deg) : 0.f;
    if (half == 0) {
        uint2 o;
        o.x = ((uint32)f32_to_bf16_bits(a1 * invd) << 16) | (uint32)f32_to_bf16_bits(a0 * invd);
        o.y = ((uint32)f32_to_bf16_bits(a3 * invd) << 16) | (uint32)f32_to_bf16_bits(a2 * invd);
        ((uint2*)meanb)[(size_t)node * 32 + c] = o;
    }
}

// ---------------- MFMA SAGE GEMM (LDS-staged weights, per-stripe blocks) ----------------
// 782 blocks x 512 threads = 8 waves x 16-row stripes (128 rows/block).
// WT (64 KB) staged in LDS once per block; B-frag reads via ds_read_b128.
// NOTE (R4): 32-row/wave (a[16]+acc[16] live) blew the register budget -> scratch
// -> 2x slower. NOTE (R10): persistent-block grid-stride version phase-locked the
// resident waves (all load, then all MFMA) and lost inter-block pipelining ->
// 25 -> 61 us. Short-lived per-stripe blocks ARE the pipeline. Keep this shape.
__global__ __launch_bounds__(512) void sage_gemm_mfma(const unsigned short* __restrict__ HB,
                                                      const unsigned short* __restrict__ MB,
                                                      const unsigned short* __restrict__ WT,
                                                      const float* __restrict__ bias,
                                                      void* __restrict__ OUTP,
                                                      int nNodes, int mode) {
    __shared__ uint4 wtl[4096];                       // 64 KB
    const int tid = threadIdx.x;
    const uint4* wt4 = (const uint4*)WT;
#pragma unroll
    for (int i = 0; i < 8; ++i)
        wtl[i * 512 + tid] = wt4[i * 512 + tid];

    const int wave = tid >> 6;
    const int lane = tid & 63;
    const int waveBase = blockIdx.x * 128 + wave * 16;
    const int m = lane & 15;
    const int quad = lane >> 4;

    int arow = waveBase + m;
    if (arow >= nNodes) arow = nNodes - 1;           // clamp loads; stores guarded below
    const uint4* hrow = (const uint4*)(HB + (size_t)arow * FEATS);
    const uint4* mrow = (const uint4*)(MB + (size_t)arow * FEATS);

    Frag a[8];
#pragma unroll
    for (int ks = 0; ks < 4; ++ks) a[ks].u = hrow[ks * 4 + quad];
#pragma unroll
    for (int ks = 0; ks < 4; ++ks) a[ks + 4].u = mrow[ks * 4 + quad];

    __syncthreads();

    f32x4 acc[8];
#pragma unroll
    for (int nt = 0; nt < 8; ++nt) acc[nt] = (f32x4){0.f, 0.f, 0.f, 0.f};

#pragma unroll
    for (int ks = 0; ks < 8; ++ks) {
#pragma unroll
        for (int nt = 0; nt < 8; ++nt) {
            Frag b;
            b.u = wtl[(nt * 8 + ks) * 64 + lane];
            acc[nt] = __builtin_amdgcn_mfma_f32_16x16x32_bf16(a[ks].v, b.v, acc[nt], 0, 0, 0);
        }
    }

#pragma unroll
    for (int nt = 0; nt < 8; ++nt) {
        const int col = nt * 16 + m;
        const float bv = bias[col];
#pragma unroll
        for (int r = 0; r < 4; ++r) {
            const int grow = waveBase + quad * 4 + r;   // C/D: row=(lane>>4)*4+reg, col=lane&15
            if (grow >= nNodes) continue;
            float v = acc[nt][r] + bv;
            if (mode) {
                v = v > 0.f ? v : 0.2f * v;
                ((unsigned short*)OUTP)[(size_t)grow * FEATS + col] = f32_to_bf16_bits(v);
            } else {
                ((float*)OUTP)[(size_t)grow * FEATS + col] = v;
            }
        }
    }
}

extern "C" void kernel_launch(void* const* d_in, const int* in_sizes, int n_in,
                              void* d_out, int out_size, void* d_ws, size_t ws_size,
                              hipStream_t stream) {
    const float* emb = (const float*)d_in[0];
    const float* W1s = (const float*)d_in[1];
    const float* W1n = (const float*)d_in[2];
    const float* b1  = (const float*)d_in[3];
    const float* W2s = (const float*)d_in[4];
    const float* W2n = (const float*)d_in[5];
    const float* b2  = (const float*)d_in[6];
    const int*   edg = (const int*)d_in[7];

    const int nE = in_sizes[7] / 2;
    const int* src = edg;
    const int* dst = edg + nE;

    const int chunk = (nE + PB - 1) / PB;            // 6250
    const int nActB = (N_NODES_C + (1 << SH) - 1) >> SH;   // 98
    const int n4 = N_NODES_C * FEATS / 4;            // 3,200,000

    const size_t bfTab = (size_t)N_NODES_C * FEATS * sizeof(unsigned short);  // 25.6 MB

    char* ws = (char*)d_ws;
    int* off      = (int*)(ws);                      // 400 KB + 4
    int* gHist    = (int*)(ws + (512 << 10));        // 128 KB
    int* bstart   = (int*)(ws + (768 << 10));        // 512 B (128+1 bucket bounds)
    int* csr      = (int*)(ws + (1 << 20));          // 6.4 MB
    uint32* ebuf  = (uint32*)(ws + (8 << 20));       // 6.4 MB
    unsigned short* wt1 = (unsigned short*)(ws + (15 << 20));   // 64 KB
    unsigned short* wt2 = (unsigned short*)(ws + (15 << 20) + (64 << 10));
    unsigned short* hb0 = (unsigned short*)(ws + (16 << 20));   // 25.6 MB
    unsigned short* h1b = (unsigned short*)((char*)hb0 + bfTab);
    unsigned short* mnb = (unsigned short*)((char*)h1b + bfTab);
    float* out = (float*)d_out;

    // ---- 1: fused prep (bucket histogram + weight swizzle + bf16 cast) ----
    prep_fused<<<PB + 32 + CAST_BLOCKS, 256, 0, stream>>>(
        dst, gHist, nE, chunk, (const float4*)emb, hb0, n4,
        W1s, W1n, wt1, W2s, W2n, wt2);

    // ---- 2-3: CSR build (fused scan+scatter, then per-bucket finalize) ----
    part_scatter<<<PB, 1024, 0, stream>>>(src, dst, gHist, bstart, ebuf, nE, chunk);
    bucket_csr<<<nActB, 1024, 0, stream>>>(ebuf, bstart, off, csr, nE);

    // ---- 4-7: layers (separate gather + gemm) ----
    const int gatherBlocks = (N_NODES_C + 3) / 4;    // 25000
    const int gemmBlocks = (N_NODES_C + 127) / 128;  // 782

    gather_mean_w2<<<gatherBlocks, 256, 0, stream>>>(hb0, csr, off, mnb, N_NODES_C);
    sage_gemm_mfma<<<gemmBlocks, 512, 0, stream>>>(hb0, mnb, wt1, b1, h1b, N_NODES_C, 1);

    gather_mean_w2<<<gatherBlocks, 256, 0, stream>>>(h1b, csr, off, mnb, N_NODES_C);
    sage_gemm_mfma<<<gemmBlocks, 512, 0, stream>>>(h1b, mnb, wt2, b2, out, N_NODES_C, 0);
}

// Round 16
// 295.361 us; speedup vs baseline: 1.2908x; 1.0393x over previous
//
// GraphSAGE MI355X — R16: gather 8-node blocks + GEMM A/bias hoist + hist x8
#include <hip/hip_runtime.h>
#include <hip/hip_bf16.h>

#define N_NODES_C 100000
#define FEATS 128
#define SH 10             // bucket shift: 1024 nodes per bucket (R8: SH=9 was -12us worse)
#define NBK 128           // padded bucket count (active: 98)
#define PB  256           // partition blocks
#define CAST_BLOCKS 1563  // (100000*128/4) / (256 threads * 8 float4/thread)

typedef unsigned int uint32;
typedef __bf16 bf16_t;
typedef bf16_t bf16x8 __attribute__((ext_vector_type(8)));
typedef float f32x4 __attribute__((ext_vector_type(4)));

union Frag { uint4 u; bf16x8 v; };

__device__ __forceinline__ unsigned short f32_to_bf16_bits(float f) {
    uint32 u = __float_as_uint(f);
    u += 0x7fffu + ((u >> 16) & 1u);   // round-to-nearest-even (finite values)
    return (unsigned short)(u >> 16);
}
__device__ __forceinline__ float bf16_lo(uint32 p) { return __uint_as_float(p << 16); }
__device__ __forceinline__ float bf16_hi(uint32 p) { return __uint_as_float(p & 0xffff0000u); }

// ---------------- Fused prep: part_count + wtprep x2 + cast ----------------
// Cast = 8 float4/thread; histogram unrolled x8 with loads batched before atomics.
// Latency-bound loops need multiple loads in flight (R3 gather-unroll lesson).
__global__ __launch_bounds__(256) void prep_fused(
    const int* __restrict__ dst, int* __restrict__ gHist, int nE, int chunk,
    const float4* __restrict__ emb4, unsigned short* __restrict__ hb0, int n4,
    const float* __restrict__ W1s, const float* __restrict__ W1n, unsigned short* __restrict__ wt1,
    const float* __restrict__ W2s, const float* __restrict__ W2n, unsigned short* __restrict__ wt2)
{
    __shared__ int h[NBK];
    const int b = blockIdx.x;
    const int tid = threadIdx.x;

    if (b < PB) {
        // --- bucket histogram over this block's edge chunk ---
        if (tid < NBK) h[tid] = 0;
        __syncthreads();
        const int b0 = b * chunk;
        const int e1 = min(b0 + chunk, nE);
        int e = b0 + tid;
        for (; e + 1792 < e1; e += 2048) {
            const int d0 = dst[e],        d1 = dst[e + 256],  d2 = dst[e + 512],  d3 = dst[e + 768];
            const int d4 = dst[e + 1024], d5 = dst[e + 1280], d6 = dst[e + 1536], d7 = dst[e + 1792];
            atomicAdd(&h[d0 >> SH], 1);
            atomicAdd(&h[d1 >> SH], 1);
            atomicAdd(&h[d2 >> SH], 1);
            atomicAdd(&h[d3 >> SH], 1);
            atomicAdd(&h[d4 >> SH], 1);
            atomicAdd(&h[d5 >> SH], 1);
            atomicAdd(&h[d6 >> SH], 1);
            atomicAdd(&h[d7 >> SH], 1);
        }
        for (; e < e1; e += 256)
            atomicAdd(&h[dst[e] >> SH], 1);
        __syncthreads();
        if (tid < NBK) gHist[tid * PB + b] = h[tid];
    } else if (b < PB + 32) {
        // --- weight pre-swizzle into B-fragment order ---
        // wt[(f*64+l)*8+j] = W[k][n], f=nt*8+ks, n=nt*16+(l&15), k=ks*32+(l>>4)*8+j
        const int which = (b - PB) >> 4;                 // 0 -> layer1, 1 -> layer2
        const float* Ws = which ? W2s : W1s;
        const float* Wn = which ? W2n : W1n;
        unsigned short* wt = which ? wt2 : wt1;
        int gid = ((b - PB) & 15) * 256 + tid;           // 0..4095
        int frag = gid >> 6, lane = gid & 63;
        int nt = frag >> 3, ks = frag & 7;
        int n = nt * 16 + (lane & 15);
        int kbase = ks * 32 + (lane >> 4) * 8;
        union { unsigned short s[8]; uint4 u; } o;
#pragma unroll
        for (int j = 0; j < 8; ++j) {
            int k = kbase + j;
            float v = (k < 128) ? Ws[(size_t)k * FEATS + n] : Wn[(size_t)(k - 128) * FEATS + n];
            o.s[j] = f32_to_bf16_bits(v);
        }
        *(uint4*)(wt + (size_t)gid * 8) = o.u;
    } else {
        // --- fp32 -> bf16 node-table cast (row-major [N][128]), 8 float4/thread ---
        const int base0 = (b - PB - 32) * 2048 + tid;
        if (base0 + 7 * 256 < n4) {
            float4 v[8];
#pragma unroll
            for (int r = 0; r < 8; ++r) v[r] = emb4[base0 + r * 256];
#pragma unroll
            for (int r = 0; r < 8; ++r) {
                union { unsigned short s[4]; uint2 u; } o;
                o.s[0] = f32_to_bf16_bits(v[r].x);
                o.s[1] = f32_to_bf16_bits(v[r].y);
                o.s[2] = f32_to_bf16_bits(v[r].z);
                o.s[3] = f32_to_bf16_bits(v[r].w);
                *(uint2*)(hb0 + (size_t)(base0 + r * 256) * 4) = o.u;
            }
        } else {
#pragma unroll
            for (int r = 0; r < 8; ++r) {
                const int i = base0 + r * 256;
                if (i < n4) {
                    float4 v = emb4[i];
                    union { unsigned short s[4]; uint2 u; } o;
                    o.s[0] = f32_to_bf16_bits(v.x);
                    o.s[1] = f32_to_bf16_bits(v.y);
                    o.s[2] = f32_to_bf16_bits(v.z);
                    o.s[3] = f32_to_bf16_bits(v.w);
                    *(uint2*)(hb0 + (size_t)i * 4) = o.u;
                }
            }
        }
    }
}

// ---------------- P2: fused scan + scatter (shfl scan; scatter unrolled x4) ----------------
// Every block redundantly computes the exclusive scan of gHist[32768]: serial
// register batch (32/thread) -> intra-wave shfl_up scan -> wave-0 combine.
// Scatter loop unrolled x4 with dst/src loads batched before the LDS atomics.
// Block 0 publishes bucket-boundary offsets bstart[k] for bucket_csr.
// LDS cursors only — global per-node cursors were a 250 us disaster (R7: cross-XCD
// atomic line migration + random 4-B scatter write amplification).
__global__ __launch_bounds__(1024) void part_scatter(const int* __restrict__ src,
                                                     const int* __restrict__ dst,
                                                     const int* __restrict__ gHist,
                                                     int* __restrict__ bstart,
                                                     uint32* __restrict__ ebuf,
                                                     int nE, int chunk) {
    __shared__ int wsum[16];
    __shared__ int cur[NBK];
    const int tid = threadIdx.x;
    const int lane = tid & 63;
    const int wid = tid >> 6;
    const int base = tid * 32;
    int pref[32];
    {
        int sum = 0;
#pragma unroll
        for (int j = 0; j < 32; ++j) {
            int v = gHist[base + j];
            pref[j] = sum;
            sum += v;
        }
        // intra-wave inclusive scan of per-thread sums (barrier-free)
        int v = sum;
#pragma unroll
        for (int d = 1; d < 64; d <<= 1) {
            int t = __shfl_up(v, d);
            if (lane >= d) v += t;
        }
        if (lane == 63) wsum[wid] = v;         // wave totals
        __syncthreads();                       // B1
        if (wid == 0) {
            int w = (lane < 16) ? wsum[lane] : 0;
            int winc = w;
#pragma unroll
            for (int d = 1; d < 16; d <<= 1) {
                int t = __shfl_up(winc, d);
                if (lane >= d) winc += t;
            }
            if (lane < 16) wsum[lane] = winc - w;   // exclusive wave offsets
        }
        __syncthreads();                       // B2
        const int ex = (v - sum) + wsum[wid];  // exclusive prefix for this thread
        // flat index f = k*PB + b (bucket-major). This block needs the scanned
        // value at f with (f & (PB-1)) == blockIdx.x, giving cursor for bucket f>>8.
#pragma unroll
        for (int j = 0; j < 32; ++j) {
            const int f = base + j;
            const int v2 = ex + pref[j];
            if ((f & (PB - 1)) == blockIdx.x) cur[f >> 8] = v2;
        }
        if (blockIdx.x == 0) {
#pragma unroll
            for (int j = 0; j < 32; ++j) {
                const int f = base + j;
                if ((f & (PB - 1)) == 0) bstart[f >> 8] = ex + pref[j];
            }
        }
    }
    __syncthreads();                           // B3
    const int b0 = blockIdx.x * chunk;
    const int e1 = min(b0 + chunk, nE);
    int e = b0 + tid;
    for (; e + 3072 < e1; e += 4096) {
        const int d0 = dst[e],        d1 = dst[e + 1024], d2 = dst[e + 2048], d3 = dst[e + 3072];
        const int s0 = src[e],        s1 = src[e + 1024], s2 = src[e + 2048], s3 = src[e + 3072];
        const int p0 = atomicAdd(&cur[d0 >> SH], 1);
        ebuf[p0] = (uint32)s0 | ((uint32)(d0 & ((1 << SH) - 1)) << 17);
        const int p1 = atomicAdd(&cur[d1 >> SH], 1);
        ebuf[p1] = (uint32)s1 | ((uint32)(d1 & ((1 << SH) - 1)) << 17);
        const int p2 = atomicAdd(&cur[d2 >> SH], 1);
        ebuf[p2] = (uint32)s2 | ((uint32)(d2 & ((1 << SH) - 1)) << 17);
        const int p3 = atomicAdd(&cur[d3 >> SH], 1);
        ebuf[p3] = (uint32)s3 | ((uint32)(d3 & ((1 << SH) - 1)) << 17);
    }
    for (; e < e1; e += 1024) {
        const int d = dst[e];
        const int pos = atomicAdd(&cur[d >> SH], 1);
        ebuf[pos] = (uint32)src[e] | ((uint32)(d & ((1 << SH) - 1)) << 17);
    }
}

// ---------------- P3: per-bucket CSR finalize (shfl scan; edge loops unrolled x4) ----------------
// csr stores src*256 = byte offset of the node's 256-B feature row (src < 2^17, fits 25 bits).
// SH=10: 98 blocks. Both edge passes unrolled x4 with ebuf loads batched before
// the LDS atomics (4 loads in flight instead of 1 — latency-bound at 38% CU use).
__global__ __launch_bounds__(1024) void bucket_csr(const uint32* __restrict__ ebuf,
                                                   const int* __restrict__ bstart,
                                                   int* __restrict__ off,
                                                   int* __restrict__ csr,
                                                   int nE) {
    __shared__ int cnt[1 << SH];
    __shared__ int wsum[16];
    const int b = blockIdx.x;
    const int tid = threadIdx.x;
    const int lane = tid & 63;
    const int wid = tid >> 6;
    const int start = bstart[b];
    const int end = bstart[b + 1];
    const int nodeBase = b << SH;
    cnt[tid] = 0;
    __syncthreads();                           // B1
    {
        int e = start + tid;
        for (; e + 3072 < end; e += 4096) {
            const uint32 p0 = ebuf[e],        p1 = ebuf[e + 1024];
            const uint32 p2 = ebuf[e + 2048], p3 = ebuf[e + 3072];
            atomicAdd(&cnt[p0 >> 17], 1);
            atomicAdd(&cnt[p1 >> 17], 1);
            atomicAdd(&cnt[p2 >> 17], 1);
            atomicAdd(&cnt[p3 >> 17], 1);
        }
        for (; e < end; e += 1024)
            atomicAdd(&cnt[ebuf[e] >> 17], 1);
    }
    __syncthreads();                           // B2
    const int own = cnt[tid];
    int v = own;
#pragma unroll
    for (int d = 1; d < 64; d <<= 1) {
        int t = __shfl_up(v, d);
        if (lane >= d) v += t;
    }
    if (lane == 63) wsum[wid] = v;
    __syncthreads();                           // B3
    if (wid == 0) {
        int w = (lane < 16) ? wsum[lane] : 0;
        int winc = w;
#pragma unroll
        for (int d = 1; d < 16; d <<= 1) {
            int t = __shfl_up(winc, d);
            if (lane >= d) winc += t;
        }
        if (lane < 16) wsum[lane] = winc - w;  // exclusive wave offsets
    }
    __syncthreads();                           // B4
    const int ex = (v - own) + wsum[wid];
    cnt[tid] = ex;                             // becomes placement cursor
    const int node = nodeBase + tid;
    if (node < N_NODES_C) off[node] = start + ex;
    if (b == gridDim.x - 1 && tid == 0) off[N_NODES_C] = nE;
    __syncthreads();                           // B5
    {
        int e = start + tid;
        for (; e + 3072 < end; e += 4096) {
            const uint32 p0 = ebuf[e],        p1 = ebuf[e + 1024];
            const uint32 p2 = ebuf[e + 2048], p3 = ebuf[e + 3072];
            const int q0 = atomicAdd(&cnt[p0 >> 17], 1);
            csr[start + q0] = (int)((p0 & 0x1FFFFu) << 8);
            const int q1 = atomicAdd(&cnt[p1 >> 17], 1);
            csr[start + q1] = (int)((p1 & 0x1FFFFu) << 8);
            const int q2 = atomicAdd(&cnt[p2 >> 17], 1);
            csr[start + q2] = (int)((p2 & 0x1FFFFu) << 8);
            const int q3 = atomicAdd(&cnt[p3 >> 17], 1);
            csr[start + q3] = (int)((p3 & 0x1FFFFu) << 8);
        }
        for (; e < end; e += 1024) {
            const uint32 p = ebuf[e];
            const int pos = atomicAdd(&cnt[p >> 17], 1);
            csr[start + pos] = (int)((p & 0x1FFFFu) << 8);   // byte offset of src row
        }
    }
}

// ---------------- Gather (mean aggregation over bf16 table) ----------------
// R16: 8 nodes per 512-thread block (12500 blocks; was 4/256 -> 25000 blocks).
// Per-wave code identical; fewer blocks cuts block-launch overhead, probing the
// 68%-occupancy ceiling. One wave per node; uint2 (8 B) per lane so one load
// covers TWO edges' 256-B rows (lanes 0-31 = even edge, 32-63 = odd edge);
// shfl_xor(32) combine. csr holds byte offsets (src*256).
// PLATEAU NOTE (R3/R5/R6/R8): uint2x8, uint2x16, uint4x32 variants all land at
// 55-59 us with FETCH pinned at the 181 MB compulsory floor -> this kernel is
// at the random-256B-row memory-system ceiling (~3.8 TB/s effective).
// Do not re-fuse with GEMM (earlier regression).
__global__ __launch_bounds__(512) void gather_mean_w2(const unsigned short* __restrict__ hb,
                                                      const int* __restrict__ csrB,
                                                      const int* __restrict__ off,
                                                      unsigned short* __restrict__ meanb,
                                                      int nNodes) {
    const int node = blockIdx.x * 8 + (threadIdx.x >> 6);
    const int lane = threadIdx.x & 63;
    if (node >= nNodes) return;
    const int start = __builtin_amdgcn_readfirstlane(off[node]);
    const int end   = __builtin_amdgcn_readfirstlane(off[node + 1]);
    const int half = lane >> 5;                 // which edge of a pair
    const int c = lane & 31;                    // uint2 column within 256-B row
    const char* base = (const char*)hb + (size_t)(c * 8);
    float a0 = 0.f, a1 = 0.f, a2 = 0.f, a3 = 0.f;
    int e = start;
    for (; e + 16 <= end; e += 16) {
        const int o0  = csrB[e + 0],  o1  = csrB[e + 1],  o2  = csrB[e + 2],  o3  = csrB[e + 3];
        const int o4  = csrB[e + 4],  o5  = csrB[e + 5],  o6  = csrB[e + 6],  o7  = csrB[e + 7];
        const int o8  = csrB[e + 8],  o9  = csrB[e + 9],  o10 = csrB[e + 10], o11 = csrB[e + 11];
        const int o12 = csrB[e + 12], o13 = csrB[e + 13], o14 = csrB[e + 14], o15 = csrB[e + 15];
        const uint2 u0 = *(const uint2*)(base + (size_t)(half ? o1  : o0));
        const uint2 u1 = *(const uint2*)(base + (size_t)(half ? o3  : o2));
        const uint2 u2 = *(const uint2*)(base + (size_t)(half ? o5  : o4));
        const uint2 u3 = *(const uint2*)(base + (size_t)(half ? o7  : o6));
        const uint2 u4 = *(const uint2*)(base + (size_t)(half ? o9  : o8));
        const uint2 u5 = *(const uint2*)(base + (size_t)(half ? o11 : o10));
        const uint2 u6 = *(const uint2*)(base + (size_t)(half ? o13 : o12));
        const uint2 u7 = *(const uint2*)(base + (size_t)(half ? o15 : o14));
        a0 += bf16_lo(u0.x); a1 += bf16_hi(u0.x); a2 += bf16_lo(u0.y); a3 += bf16_hi(u0.y);
        a0 += bf16_lo(u1.x); a1 += bf16_hi(u1.x); a2 += bf16_lo(u1.y); a3 += bf16_hi(u1.y);
        a0 += bf16_lo(u2.x); a1 += bf16_hi(u2.x); a2 += bf16_lo(u2.y); a3 += bf16_hi(u2.y);
        a0 += bf16_lo(u3.x); a1 += bf16_hi(u3.x); a2 += bf16_lo(u3.y); a3 += bf16_hi(u3.y);
        a0 += bf16_lo(u4.x); a1 += bf16_hi(u4.x); a2 += bf16_lo(u4.y); a3 += bf16_hi(u4.y);
        a0 += bf16_lo(u5.x); a1 += bf16_hi(u5.x); a2 += bf16_lo(u5.y); a3 += bf16_hi(u5.y);
        a0 += bf16_lo(u6.x); a1 += bf16_hi(u6.x); a2 += bf16_lo(u6.y); a3 += bf16_hi(u6.y);
        a0 += bf16_lo(u7.x); a1 += bf16_hi(u7.x); a2 += bf16_lo(u7.y); a3 += bf16_hi(u7.y);
    }
    if (e + 8 <= end) {
        const int o0 = csrB[e + 0], o1 = csrB[e + 1], o2 = csrB[e + 2], o3 = csrB[e + 3];
        const int o4 = csrB[e + 4], o5 = csrB[e + 5], o6 = csrB[e + 6], o7 = csrB[e + 7];
        const uint2 u0 = *(const uint2*)(base + (size_t)(half ? o1 : o0));
        const uint2 u1 = *(const uint2*)(base + (size_t)(half ? o3 : o2));
        const uint2 u2 = *(const uint2*)(base + (size_t)(half ? o5 : o4));
        const uint2 u3 = *(const uint2*)(base + (size_t)(half ? o7 : o6));
        a0 += bf16_lo(u0.x); a1 += bf16_hi(u0.x); a2 += bf16_lo(u0.y); a3 += bf16_hi(u0.y);
        a0 += bf16_lo(u1.x); a1 += bf16_hi(u1.x); a2 += bf16_lo(u1.y); a3 += bf16_hi(u1.y);
        a0 += bf16_lo(u2.x); a1 += bf16_hi(u2.x); a2 += bf16_lo(u2.y); a3 += bf16_hi(u2.y);
        a0 += bf16_lo(u3.x); a1 += bf16_hi(u3.x); a2 += bf16_lo(u3.y); a3 += bf16_hi(u3.y);
        e += 8;
    }
    if (e + 4 <= end) {
        const int o0 = csrB[e + 0], o1 = csrB[e + 1], o2 = csrB[e + 2], o3 = csrB[e + 3];
        const uint2 u0 = *(const uint2*)(base + (size_t)(half ? o1 : o0));
        const uint2 u1 = *(const uint2*)(base + (size_t)(half ? o3 : o2));
        a0 += bf16_lo(u0.x); a1 += bf16_hi(u0.x); a2 += bf16_lo(u0.y); a3 += bf16_hi(u0.y);
        a0 += bf16_lo(u1.x); a1 += bf16_hi(u1.x); a2 += bf16_lo(u1.y); a3 += bf16_hi(u1.y);
        e += 4;
    }
    if (e + 2 <= end) {
        const int o0 = csrB[e + 0], o1 = csrB[e + 1];
        const uint2 u = *(const uint2*)(base + (size_t)(half ? o1 : o0));
        a0 += bf16_lo(u.x); a1 += bf16_hi(u.x); a2 += bf16_lo(u.y); a3 += bf16_hi(u.y);
        e += 2;
    }
    if (e < end && half == 0) {
        const uint2 u = *(const uint2*)(base + (size_t)csrB[e]);
        a0 += bf16_lo(u.x); a1 += bf16_hi(u.x); a2 += bf16_lo(u.y); a3 += bf16_hi(u.y);
    }
    // combine even-edge / odd-edge partial sums held in lane pairs (l, l^32)
    a0 += __shfl_xor(a0, 32);
    a1 += __shfl_xor(a1, 32);
    a2 += __shfl_xor(a2, 32);
    a3 += __shfl_xor(a3, 32);
    const int deg = end - start;
    const float invd = (deg > 0) ? (1.f / (float)deg) : 0.f;
    if (half == 0) {
        uint2 o;
        o.x = ((uint32)f32_to_bf16_bits(a1 * invd) << 16) | (uint32)f32_to_bf16_bits(a0 * invd);
        o.y = ((uint32)f32_to_bf16_bits(a3 * invd) << 16) | (uint32)f32_to_bf16_bits(a2 * invd);
        ((uint2*)meanb)[(size_t)node * 32 + c] = o;
    }
}

// ---------------- MFMA SAGE GEMM (LDS-staged weights, per-stripe blocks) ----------------
// 782 blocks x 512 threads = 8 waves x 16-row stripes (128 rows/block).
// WT (64 KB) staged in LDS once per block; B-frag reads via ds_read_b128.
// R16: A-fragment + bias loads issued BEFORE the staging loop so their HBM
// latency hides under the 8 staging loads (previously issued after).
// NOTE (R4): 32-row/wave (a[16]+acc[16] live) blew the register budget -> scratch
// -> 2x slower. NOTE (R10): persistent-block grid-stride version phase-locked the
// resident waves and lost inter-block pipelining -> 25 -> 61 us. Short-lived
// per-stripe blocks ARE the pipeline. 512-thr/64KB = 2 blocks/CU is the
// LDS-constrained optimum (1024-thr would drop to 1 block/CU -> drain bubbles).
__global__ __launch_bounds__(512) void sage_gemm_mfma(const unsigned short* __restrict__ HB,
                                                      const unsigned short* __restrict__ MB,
                                                      const unsigned short* __restrict__ WT,
                                                      const float* __restrict__ bias,
                                                      void* __restrict__ OUTP,
                                                      int nNodes, int mode) {
    __shared__ uint4 wtl[4096];                       // 64 KB
    const int tid = threadIdx.x;
    const int wave = tid >> 6;
    const int lane = tid & 63;
    const int waveBase = blockIdx.x * 128 + wave * 16;
    const int m = lane & 15;
    const int quad = lane >> 4;

    int arow = waveBase + m;
    if (arow >= nNodes) arow = nNodes - 1;           // clamp loads; stores guarded below
    const uint4* hrow = (const uint4*)(HB + (size_t)arow * FEATS);
    const uint4* mrow = (const uint4*)(MB + (size_t)arow * FEATS);

    // Issue A-fragment + bias loads FIRST (latency hides under staging below).
    Frag a[8];
#pragma unroll
    for (int ks = 0; ks < 4; ++ks) a[ks].u = hrow[ks * 4 + quad];
#pragma unroll
    for (int ks = 0; ks < 4; ++ks) a[ks + 4].u = mrow[ks * 4 + quad];
    float bv[8];
#pragma unroll
    for (int nt = 0; nt < 8; ++nt) bv[nt] = bias[nt * 16 + m];

    const uint4* wt4 = (const uint4*)WT;
#pragma unroll
    for (int i = 0; i < 8; ++i)
        wtl[i * 512 + tid] = wt4[i * 512 + tid];

    __syncthreads();

    f32x4 acc[8];
#pragma unroll
    for (int nt = 0; nt < 8; ++nt) acc[nt] = (f32x4){0.f, 0.f, 0.f, 0.f};

#pragma unroll
    for (int ks = 0; ks < 8; ++ks) {
#pragma unroll
        for (int nt = 0; nt < 8; ++nt) {
            Frag b;
            b.u = wtl[(nt * 8 + ks) * 64 + lane];
            acc[nt] = __builtin_amdgcn_mfma_f32_16x16x32_bf16(a[ks].v, b.v, acc[nt], 0, 0, 0);
        }
    }

#pragma unroll
    for (int nt = 0; nt < 8; ++nt) {
        const int col = nt * 16 + m;
#pragma unroll
        for (int r = 0; r < 4; ++r) {
            const int grow = waveBase + quad * 4 + r;   // C/D: row=(lane>>4)*4+reg, col=lane&15
            if (grow >= nNodes) continue;
            float v = acc[nt][r] + bv[nt];
            if (mode) {
                v = v > 0.f ? v : 0.2f * v;
                ((unsigned short*)OUTP)[(size_t)grow * FEATS + col] = f32_to_bf16_bits(v);
            } else {
                ((float*)OUTP)[(size_t)grow * FEATS + col] = v;
            }
        }
    }
}

extern "C" void kernel_launch(void* const* d_in, const int* in_sizes, int n_in,
                              void* d_out, int out_size, void* d_ws, size_t ws_size,
                              hipStream_t stream) {
    const float* emb = (const float*)d_in[0];
    const float* W1s = (const float*)d_in[1];
    const float* W1n = (const float*)d_in[2];
    const float* b1  = (const float*)d_in[3];
    const float* W2s = (const float*)d_in[4];
    const float* W2n = (const float*)d_in[5];
    const float* b2  = (const float*)d_in[6];
    const int*   edg = (const int*)d_in[7];

    const int nE = in_sizes[7] / 2;
    const int* src = edg;
    const int* dst = edg + nE;

    const int chunk = (nE + PB - 1) / PB;            // 6250
    const int nActB = (N_NODES_C + (1 << SH) - 1) >> SH;   // 98
    const int n4 = N_NODES_C * FEATS / 4;            // 3,200,000

    const size_t bfTab = (size_t)N_NODES_C * FEATS * sizeof(unsigned short);  // 25.6 MB

    char* ws = (char*)d_ws;
    int* off      = (int*)(ws);                      // 400 KB + 4
    int* gHist    = (int*)(ws + (512 << 10));        // 128 KB
    int* bstart   = (int*)(ws + (768 << 10));        // 512 B (128+1 bucket bounds)
    int* csr      = (int*)(ws + (1 << 20));          // 6.4 MB
    uint32* ebuf  = (uint32*)(ws + (8 << 20));       // 6.4 MB
    unsigned short* wt1 = (unsigned short*)(ws + (15 << 20));   // 64 KB
    unsigned short* wt2 = (unsigned short*)(ws + (15 << 20) + (64 << 10));
    unsigned short* hb0 = (unsigned short*)(ws + (16 << 20));   // 25.6 MB
    unsigned short* h1b = (unsigned short*)((char*)hb0 + bfTab);
    unsigned short* mnb = (unsigned short*)((char*)h1b + bfTab);
    float* out = (float*)d_out;

    // ---- 1: fused prep (bucket histogram + weight swizzle + bf16 cast) ----
    prep_fused<<<PB + 32 + CAST_BLOCKS, 256, 0, stream>>>(
        dst, gHist, nE, chunk, (const float4*)emb, hb0, n4,
        W1s, W1n, wt1, W2s, W2n, wt2);

    // ---- 2-3: CSR build (fused scan+scatter, then per-bucket finalize) ----
    part_scatter<<<PB, 1024, 0, stream>>>(src, dst, gHist, bstart, ebuf, nE, chunk);
    bucket_csr<<<nActB, 1024, 0, stream>>>(ebuf, bstart, off, csr, nE);

    // ---- 4-7: layers (separate gather + gemm) ----
    const int gatherBlocks = (N_NODES_C + 7) / 8;    // 12500
    const int gemmBlocks = (N_NODES_C + 127) / 128;  // 782

    gather_mean_w2<<<gatherBlocks, 512, 0, stream>>>(hb0, csr, off, mnb, N_NODES_C);
    sage_gemm_mfma<<<gemmBlocks, 512, 0, stream>>>(hb0, mnb, wt1, b1, h1b, N_NODES_C, 1);

    gather_mean_w2<<<gatherBlocks, 512, 0, stream>>>(h1b, csr, off, mnb, N_NODES_C);
    sage_gemm_mfma<<<gemmBlocks, 512, 0, stream>>>(h1b, mnb, wt2, b2, out, N_NODES_C, 0);
}